// Round 1
// baseline (768.011 us; speedup 1.0000x reference)
//
#include <hip/hip_runtime.h>

#define E_N 200000
#define M_N 3200000
#define SCAN_CHUNK 2048
#define NB1 98          // ceil(E_N / SCAN_CHUNK)

// bucket sort geometry
#define NBUCK 1563      // ceil(E_N / 128), 128 dst per bucket
#define NCHUNK 160      // m-chunks (one block each)
#define CH 20000        // pairs per chunk: NCHUNK*CH == M_N
#define BLEN (NBUCK * NCHUNK)   // 250080
#define NB2 123         // ceil(BLEN / SCAN_CHUNK)
#define SMAX 4096       // max records per bucket handled in LDS (mean 2048, ~45 sigma)

typedef __attribute__((ext_vector_type(8))) short bf16x8;      // MFMA A/B frag
typedef __attribute__((ext_vector_type(4))) float f32x4;       // MFMA C/D frag
typedef __attribute__((ext_vector_type(8))) _Float16 f16x8;    // 16B of f16

// fp32 -> bf16 (round to nearest even), raw short
__device__ __forceinline__ short f2bf(float f) {
    union { float f; unsigned u; } x; x.f = f;
    unsigned r = x.u + 0x7fffu + ((x.u >> 16) & 1u);
    return (short)(r >> 16);
}

// ---------------------------------------------------------------------------
// qkv via MFMA: q (fp32, to d_out) and k/v (f16) = x @ W + b.
// One wave per 16-row stripe; block = 4 waves = 64 rows/iter. E_N % 64 == 0.
// ---------------------------------------------------------------------------
__global__ __launch_bounds__(256) void qkv_mfma(
    const float* __restrict__ x,
    const float* __restrict__ Wq, const float* __restrict__ bq,
    const float* __restrict__ Wk, const float* __restrict__ bk,
    const float* __restrict__ Wv, const float* __restrict__ bv,
    float* __restrict__ q, _Float16* __restrict__ k, _Float16* __restrict__ v)
{
    const int w    = threadIdx.x >> 6;
    const int lane = threadIdx.x & 63;
    const int quad = lane >> 4;
    const int m    = lane & 15;

    bf16x8 Bq[4][2], Bk[4][2], Bv[4][2];
    float  bqv[4], bkv[4], bvv[4];
    #pragma unroll
    for (int ct = 0; ct < 4; ct++) {
        int cc = ct * 16 + m;
        bqv[ct] = bq[cc]; bkv[ct] = bk[cc]; bvv[ct] = bv[cc];
        #pragma unroll
        for (int kb = 0; kb < 2; kb++) {
            #pragma unroll
            for (int j = 0; j < 8; j++) {
                int kk = kb * 32 + quad * 8 + j;
                Bq[ct][kb][j] = f2bf(Wq[kk * 64 + cc]);
                Bk[ct][kb][j] = f2bf(Wk[kk * 64 + cc]);
                Bv[ct][kb][j] = f2bf(Wv[kk * 64 + cc]);
            }
        }
    }

    for (int row0 = blockIdx.x * 64 + w * 16; row0 < E_N; row0 += gridDim.x * 64) {
        const float* xr = x + (long long)(row0 + m) * 64 + quad * 8;
        bf16x8 A[2];
        #pragma unroll
        for (int kb = 0; kb < 2; kb++) {
            float4 p0 = *(const float4*)(xr + kb * 32);
            float4 p1 = *(const float4*)(xr + kb * 32 + 4);
            A[kb][0] = f2bf(p0.x); A[kb][1] = f2bf(p0.y);
            A[kb][2] = f2bf(p0.z); A[kb][3] = f2bf(p0.w);
            A[kb][4] = f2bf(p1.x); A[kb][5] = f2bf(p1.y);
            A[kb][6] = f2bf(p1.z); A[kb][7] = f2bf(p1.w);
        }

        #pragma unroll
        for (int ct = 0; ct < 4; ct++) {
            f32x4 aq = {bqv[ct], bqv[ct], bqv[ct], bqv[ct]};
            f32x4 ak = {bkv[ct], bkv[ct], bkv[ct], bkv[ct]};
            f32x4 av = {bvv[ct], bvv[ct], bvv[ct], bvv[ct]};
            aq = __builtin_amdgcn_mfma_f32_16x16x32_bf16(A[0], Bq[ct][0], aq, 0, 0, 0);
            aq = __builtin_amdgcn_mfma_f32_16x16x32_bf16(A[1], Bq[ct][1], aq, 0, 0, 0);
            ak = __builtin_amdgcn_mfma_f32_16x16x32_bf16(A[0], Bk[ct][0], ak, 0, 0, 0);
            ak = __builtin_amdgcn_mfma_f32_16x16x32_bf16(A[1], Bk[ct][1], ak, 0, 0, 0);
            av = __builtin_amdgcn_mfma_f32_16x16x32_bf16(A[0], Bv[ct][0], av, 0, 0, 0);
            av = __builtin_amdgcn_mfma_f32_16x16x32_bf16(A[1], Bv[ct][1], av, 0, 0, 0);
            #pragma unroll
            for (int i = 0; i < 4; i++) {
                long long off = (long long)(row0 + quad * 4 + i) * 64 + ct * 16 + m;
                q[off] = aq[i];
                k[off] = (_Float16)ak[i];
                v[off] = (_Float16)av[i];
            }
        }
    }
}

// ---------------------------------------------------------------------------
// per-dst histogram (for aggregate + dst-level scan)
// ---------------------------------------------------------------------------
__global__ __launch_bounds__(256) void hist_kernel(
    const int* __restrict__ e2e, int* __restrict__ counts)
{
    int m4 = (blockIdx.x * 256 + threadIdx.x) * 4;
    if (m4 < M_N) {
        int4 d = *(const int4*)(e2e + M_N + m4);
        atomicAdd(&counts[d.x], 1);
        atomicAdd(&counts[d.y], 1);
        atomicAdd(&counts[d.z], 1);
        atomicAdd(&counts[d.w], 1);
    }
}

// ---------------------------------------------------------------------------
// generic 2-level exclusive scan (chunk size SCAN_CHUNK)
// ---------------------------------------------------------------------------
__global__ __launch_bounds__(256) void scan1_kernel(
    const int* __restrict__ counts, int* __restrict__ cursor,
    int* __restrict__ blocksums, int len)
{
    __shared__ int s[256];
    const int t = threadIdx.x;
    const int base = blockIdx.x * SCAN_CHUNK + t * 8;

    int vals[8];
    int tot = 0;
    #pragma unroll
    for (int j = 0; j < 8; j++) {
        int idx = base + j;
        vals[j] = (idx < len) ? counts[idx] : 0;
        tot += vals[j];
    }
    s[t] = tot;
    __syncthreads();
    for (int off = 1; off < 256; off <<= 1) {
        int add = (t >= off) ? s[t - off] : 0;
        __syncthreads();
        s[t] += add;
        __syncthreads();
    }
    int excl = (t == 0) ? 0 : s[t - 1];
    if (t == 255) blocksums[blockIdx.x] = s[255];

    int run = excl;
    #pragma unroll
    for (int j = 0; j < 8; j++) {
        int idx = base + j;
        if (idx < len) cursor[idx] = run;
        run += vals[j];
    }
}

__global__ __launch_bounds__(128) void scan2_kernel(
    const int* __restrict__ blocksums, int* __restrict__ blockoff, int nb)
{
    __shared__ int s[128];
    const int t = threadIdx.x;
    s[t] = (t < nb) ? blocksums[t] : 0;
    __syncthreads();
    for (int off = 1; off < 128; off <<= 1) {
        int add = (t >= off) ? s[t - off] : 0;
        __syncthreads();
        s[t] += add;
        __syncthreads();
    }
    if (t < nb) blockoff[t] = (t == 0) ? 0 : s[t - 1];
}

// ---------------------------------------------------------------------------
// per-(bucket,chunk) histogram: bucket = dst>>7, one block per m-chunk.
// ---------------------------------------------------------------------------
__global__ __launch_bounds__(1024) void bhist_kernel(
    const int* __restrict__ e2e, int* __restrict__ bcnt)
{
    __shared__ int lc[NBUCK];
    const int c = blockIdx.x;
    for (int i = threadIdx.x; i < NBUCK; i += 1024) lc[i] = 0;
    __syncthreads();
    const int m0 = c * CH;
    for (int i = threadIdx.x * 4; i < CH; i += 1024 * 4) {
        int4 d = *(const int4*)(e2e + M_N + m0 + i);
        atomicAdd(&lc[d.x >> 7], 1);
        atomicAdd(&lc[d.y >> 7], 1);
        atomicAdd(&lc[d.z >> 7], 1);
        atomicAdd(&lc[d.w >> 7], 1);
    }
    __syncthreads();
    for (int i = threadIdx.x; i < NBUCK; i += 1024) bcnt[i * NCHUNK + c] = lc[i];
}

// ---------------------------------------------------------------------------
// deterministic scatter into bucket order: block c owns m-range [c*CH,(c+1)*CH)
// and an exact disjoint slot range per bucket (from the bcnt scan). Writes of
// one bucket within a block are consecutive -> L2 lines fill before eviction.
// meta = (dst_low7 << 18) | src  (src < 2^18), bias converted to f16.
// ---------------------------------------------------------------------------
__global__ __launch_bounds__(1024) void scatter_bucket(
    const int* __restrict__ e2e, const float* __restrict__ bias,
    const int* __restrict__ bcur0, const int* __restrict__ boff2,
    int* __restrict__ meta, _Float16* __restrict__ bias_s)
{
    __shared__ int lcur[NBUCK];
    const int c = blockIdx.x;
    for (int i = threadIdx.x; i < NBUCK; i += 1024) {
        int idx = i * NCHUNK + c;
        lcur[i] = bcur0[idx] + boff2[idx >> 11];
    }
    __syncthreads();
    const int m0 = c * CH;
    for (int i = threadIdx.x; i < CH; i += 1024) {
        int m = m0 + i;
        int src = e2e[m];
        int dst = e2e[M_N + m];
        int pos = atomicAdd(&lcur[dst >> 7], 1);
        meta[pos] = ((dst & 127) << 18) | src;

        float4 b0 = *(const float4*)(bias + (long long)m * 8);
        float4 b1 = *(const float4*)(bias + (long long)m * 8 + 4);
        f16x8 bb;
        bb[0] = (_Float16)b0.x; bb[1] = (_Float16)b0.y;
        bb[2] = (_Float16)b0.z; bb[3] = (_Float16)b0.w;
        bb[4] = (_Float16)b1.x; bb[5] = (_Float16)b1.y;
        bb[6] = (_Float16)b1.z; bb[7] = (_Float16)b1.w;
        *(f16x8*)(bias_s + (long long)pos * 8) = bb;
    }
}

// ---------------------------------------------------------------------------
// finish the sort within each bucket (128 dst values) entirely in LDS,
// permuting meta->sorted(src) and bias_s in place. Coalesced, L2/L3-warm.
// __syncthreads drains vmcnt(0) so all reads complete before in-place writes.
// ---------------------------------------------------------------------------
__global__ __launch_bounds__(256) void bucket_permute(
    const int* __restrict__ cursor, const int* __restrict__ boff,
    int* __restrict__ meta, _Float16* __restrict__ bias_s)
{
    __shared__ int smeta[SMAX];
    __shared__ int cnt[128];
    __shared__ int scn[128];
    const int b = blockIdx.x;
    const int t = threadIdx.x;
    const int d0 = b << 7;
    const int bs = cursor[d0] + boff[d0 >> 11];
    const int d1 = d0 + 128;
    const int be = (d1 < E_N) ? (cursor[d1] + boff[d1 >> 11]) : M_N;
    int n = be - bs;
    if (n > SMAX) n = SMAX;   // ~45 sigma; memory-safety clamp only

    if (t < 128) cnt[t] = 0;
    __syncthreads();
    #pragma unroll
    for (int r = 0; r < SMAX / 256; r++) {
        int i = t + r * 256;
        if (i < n) {
            int mm = meta[bs + i];
            smeta[i] = mm;
            atomicAdd(&cnt[mm >> 18], 1);
        }
    }
    __syncthreads();
    if (t < 128) scn[t] = cnt[t];
    __syncthreads();
    for (int off = 1; off < 128; off <<= 1) {
        int v = 0;
        if (t < 128 && t >= off) v = scn[t - off];
        __syncthreads();
        if (t < 128) scn[t] += v;
        __syncthreads();
    }
    if (t < 128) cnt[t] = scn[t] - cnt[t];   // exclusive base; cnt reused as cursor
    __syncthreads();

    int    pos[SMAX / 256];
    f16x8  bb[SMAX / 256];
    #pragma unroll
    for (int r = 0; r < SMAX / 256; r++) {
        int i = t + r * 256;
        if (i < n) {
            int mm = smeta[i];
            pos[r] = bs + atomicAdd(&cnt[mm >> 18], 1);
            bb[r]  = *(const f16x8*)(bias_s + (long long)(bs + i) * 8);
        }
    }
    __syncthreads();   // all reads drained (vmcnt 0) before any in-place write
    #pragma unroll
    for (int r = 0; r < SMAX / 256; r++) {
        int i = t + r * 256;
        if (i < n) {
            meta[pos[r]] = smeta[i] & 0x3FFFF;
            *(f16x8*)(bias_s + (long long)pos[r] * 8) = bb[r];
        }
    }
}

// ---------------------------------------------------------------------------
// aggregate: one wave per dst edge, 8 pairs in parallel per batch.
// Dot phase: lane = ps*8 + t (pair slot, head); accum phase: lane = h*8 + d.
// cursor is PRISTINE (start offset); end = start + counts[e].
// ---------------------------------------------------------------------------
__global__ __launch_bounds__(256) void aggregate_kernel(
    const _Float16* __restrict__ k, const _Float16* __restrict__ v,
    const _Float16* __restrict__ bias_s,
    const int* __restrict__ counts, const int* __restrict__ cursor,
    const int* __restrict__ blockoff,
    const int* __restrict__ sorted,
    float* __restrict__ qmsg)
{
    const int wid  = threadIdx.x >> 6;
    const int lane = threadIdx.x & 63;
    const int ps   = lane >> 3;
    const int t    = lane & 7;

    for (int e = blockIdx.x * 4 + wid; e < E_N; e += gridDim.x * 4) {
        float qv = qmsg[(long long)e * 64 + lane];

        float qs[8];
        #pragma unroll
        for (int j = 0; j < 8; j++) qs[j] = __shfl(qv, t * 8 + j, 64);

        int start = cursor[e] + blockoff[e >> 11];
        int cnt   = counts[e];
        int end   = start + cnt;

        float acc = 0.0f, wsum = 0.0f;
        for (int i = start; i < end; i += 8) {
            int idx = i + ps;
            bool valid = idx < end;
            int src = valid ? sorted[idx] : 0;
            float bs = valid ? (float)bias_s[(long long)idx * 8 + t] : 0.0f;

            f16x8 kk = *(const f16x8*)(k + (long long)src * 64 + t * 8);
            float dot = 0.0f;
            #pragma unroll
            for (int j = 0; j < 8; j++) dot = fmaf(qs[j], (float)kk[j], dot);

            float w = valid ? __expf(fmaf(dot, 0.35355339059327373f, bs)) : 0.0f;

            int   srcj[8];
            float wj[8];
            #pragma unroll
            for (int j = 0; j < 8; j++) {
                srcj[j] = __shfl(src, j * 8, 64);
                wj[j]   = __shfl(w, j * 8 + ps, 64);
            }
            #pragma unroll
            for (int j = 0; j < 8; j++) {
                float vv = (float)v[(long long)srcj[j] * 64 + lane];
                acc  += wj[j] * vv;
                wsum += wj[j];
            }
        }
        qmsg[(long long)e * 64 + lane] = acc / (wsum + 1e-16f);
    }
}

// ---------------------------------------------------------------------------
// out = msg @ Wo + bo via MFMA, in-place on d_out.
// ---------------------------------------------------------------------------
__global__ __launch_bounds__(256) void out_mfma(
    const float* __restrict__ Wo, const float* __restrict__ bo,
    float* __restrict__ out)
{
    const int w    = threadIdx.x >> 6;
    const int lane = threadIdx.x & 63;
    const int quad = lane >> 4;
    const int m    = lane & 15;

    bf16x8 B[4][2];
    float  bov[4];
    #pragma unroll
    for (int ct = 0; ct < 4; ct++) {
        int cc = ct * 16 + m;
        bov[ct] = bo[cc];
        #pragma unroll
        for (int kb = 0; kb < 2; kb++) {
            #pragma unroll
            for (int j = 0; j < 8; j++) {
                int kk = kb * 32 + quad * 8 + j;
                B[ct][kb][j] = f2bf(Wo[kk * 64 + cc]);
            }
        }
    }

    for (int row0 = blockIdx.x * 64 + w * 16; row0 < E_N; row0 += gridDim.x * 64) {
        const float* xr = out + (long long)(row0 + m) * 64 + quad * 8;
        bf16x8 A[2];
        #pragma unroll
        for (int kb = 0; kb < 2; kb++) {
            float4 p0 = *(const float4*)(xr + kb * 32);
            float4 p1 = *(const float4*)(xr + kb * 32 + 4);
            A[kb][0] = f2bf(p0.x); A[kb][1] = f2bf(p0.y);
            A[kb][2] = f2bf(p0.z); A[kb][3] = f2bf(p0.w);
            A[kb][4] = f2bf(p1.x); A[kb][5] = f2bf(p1.y);
            A[kb][6] = f2bf(p1.z); A[kb][7] = f2bf(p1.w);
        }

        f32x4 acc[4];
        #pragma unroll
        for (int ct = 0; ct < 4; ct++) {
            acc[ct] = (f32x4){bov[ct], bov[ct], bov[ct], bov[ct]};
            acc[ct] = __builtin_amdgcn_mfma_f32_16x16x32_bf16(A[0], B[ct][0], acc[ct], 0, 0, 0);
            acc[ct] = __builtin_amdgcn_mfma_f32_16x16x32_bf16(A[1], B[ct][1], acc[ct], 0, 0, 0);
        }
        #pragma unroll
        for (int ct = 0; ct < 4; ct++) {
            #pragma unroll
            for (int i = 0; i < 4; i++) {
                out[(long long)(row0 + quad * 4 + i) * 64 + ct * 16 + m] = acc[ct][i];
            }
        }
    }
}

extern "C" void kernel_launch(void* const* d_in, const int* in_sizes, int n_in,
                              void* d_out, int out_size, void* d_ws, size_t ws_size,
                              hipStream_t stream) {
    const float* x    = (const float*)d_in[0];
    const int*   e2e  = (const int*)  d_in[1];
    const float* bias = (const float*)d_in[2];
    const float* Wq   = (const float*)d_in[3];
    const float* bq   = (const float*)d_in[4];
    const float* Wk   = (const float*)d_in[5];
    const float* bk   = (const float*)d_in[6];
    const float* Wv   = (const float*)d_in[7];
    const float* bv   = (const float*)d_in[8];
    const float* Wo   = (const float*)d_in[9];
    const float* bo   = (const float*)d_in[10];
    float* out = (float*)d_out;   // q buffer -> msg buffer -> final out (in place)

    // ws: k_h[12.8M f16] | v_h[12.8M f16] | counts | cursor | bsum | boff |
    //     sorted[3.2M int] | bias_s[25.6M f16] | bcnt[BLEN] | bcur0[BLEN] |
    //     bsum2[128] | boff2[128]   (total ~119 MB)
    _Float16* kh     = (_Float16*)d_ws;
    _Float16* vh     = kh + (long long)E_N * 64;
    int*      counts = (int*)(vh + (long long)E_N * 64);
    int*      cursor = counts + E_N;
    int*      bsum   = cursor + E_N;
    int*      boff   = bsum + 128;
    int*      sorted = boff + 128;
    _Float16* bias_s = (_Float16*)(sorted + M_N);
    int*      bcnt   = (int*)(bias_s + (long long)M_N * 8);
    int*      bcur0  = bcnt + BLEN;
    int*      bsum2  = bcur0 + BLEN;
    int*      boff2  = bsum2 + 128;

    hipMemsetAsync(counts, 0, (size_t)E_N * sizeof(int), stream);

    qkv_mfma<<<640, 256, 0, stream>>>(x, Wq, bq, Wk, bk, Wv, bv, out, kh, vh);

    // dst-level histogram + scan (pristine; consumed by aggregate + permute)
    hist_kernel<<<M_N / 1024, 256, 0, stream>>>(e2e, counts);
    scan1_kernel<<<NB1, 256, 0, stream>>>(counts, cursor, bsum, E_N);
    scan2_kernel<<<1, 128, 0, stream>>>(bsum, boff, NB1);

    // (bucket,chunk) histogram + scan -> exact disjoint slot ranges per block
    bhist_kernel<<<NCHUNK, 1024, 0, stream>>>(e2e, bcnt);
    scan1_kernel<<<NB2, 256, 0, stream>>>(bcnt, bcur0, bsum2, BLEN);
    scan2_kernel<<<1, 128, 0, stream>>>(bsum2, boff2, NB2);

    // deterministic block-local scatter into bucket order, then finish in LDS
    scatter_bucket<<<NCHUNK, 1024, 0, stream>>>(e2e, bias, bcur0, boff2,
                                                sorted, bias_s);
    bucket_permute<<<NBUCK, 256, 0, stream>>>(cursor, boff, sorted, bias_s);

    aggregate_kernel<<<8192, 256, 0, stream>>>(kh, vh, bias_s, counts, cursor,
                                               boff, sorted, out);

    out_mfma<<<640, 256, 0, stream>>>(Wo, bo, out);
}

// Round 2
// 745.740 us; speedup vs baseline: 1.0299x; 1.0299x over previous
//
#include <hip/hip_runtime.h>

#define E_N 200000
#define M_N 3200000
#define SCAN_CHUNK 2048
#define NB1 98          // ceil(E_N / SCAN_CHUNK)

// bucket sort geometry
#define NBUCK 1563      // ceil(E_N / 128), 128 dst per bucket
#define NCHUNK 320      // m-chunks (one block each)
#define CH 10000        // pairs per chunk: NCHUNK*CH == M_N
#define BLEN (NBUCK * NCHUNK)   // 500160
#define NB2 245         // ceil(BLEN / SCAN_CHUNK)
#define SMAX 4096       // max records per bucket handled in LDS (mean 2048, ~45 sigma)

typedef __attribute__((ext_vector_type(8))) short bf16x8;      // MFMA A/B frag
typedef __attribute__((ext_vector_type(4))) float f32x4;       // MFMA C/D frag
typedef __attribute__((ext_vector_type(8))) _Float16 f16x8;    // 16B of f16

// fp32 -> bf16 (round to nearest even), raw short
__device__ __forceinline__ short f2bf(float f) {
    union { float f; unsigned u; } x; x.f = f;
    unsigned r = x.u + 0x7fffu + ((x.u >> 16) & 1u);
    return (short)(r >> 16);
}

// ---------------------------------------------------------------------------
// qkv via MFMA: q (fp32, to d_out) and k/v (f16) = x @ W + b.
// One wave per 16-row stripe; block = 4 waves = 64 rows/iter. E_N % 64 == 0.
// ---------------------------------------------------------------------------
__global__ __launch_bounds__(256) void qkv_mfma(
    const float* __restrict__ x,
    const float* __restrict__ Wq, const float* __restrict__ bq,
    const float* __restrict__ Wk, const float* __restrict__ bk,
    const float* __restrict__ Wv, const float* __restrict__ bv,
    float* __restrict__ q, _Float16* __restrict__ k, _Float16* __restrict__ v)
{
    const int w    = threadIdx.x >> 6;
    const int lane = threadIdx.x & 63;
    const int quad = lane >> 4;
    const int m    = lane & 15;

    bf16x8 Bq[4][2], Bk[4][2], Bv[4][2];
    float  bqv[4], bkv[4], bvv[4];
    #pragma unroll
    for (int ct = 0; ct < 4; ct++) {
        int cc = ct * 16 + m;
        bqv[ct] = bq[cc]; bkv[ct] = bk[cc]; bvv[ct] = bv[cc];
        #pragma unroll
        for (int kb = 0; kb < 2; kb++) {
            #pragma unroll
            for (int j = 0; j < 8; j++) {
                int kk = kb * 32 + quad * 8 + j;
                Bq[ct][kb][j] = f2bf(Wq[kk * 64 + cc]);
                Bk[ct][kb][j] = f2bf(Wk[kk * 64 + cc]);
                Bv[ct][kb][j] = f2bf(Wv[kk * 64 + cc]);
            }
        }
    }

    for (int row0 = blockIdx.x * 64 + w * 16; row0 < E_N; row0 += gridDim.x * 64) {
        const float* xr = x + (long long)(row0 + m) * 64 + quad * 8;
        bf16x8 A[2];
        #pragma unroll
        for (int kb = 0; kb < 2; kb++) {
            float4 p0 = *(const float4*)(xr + kb * 32);
            float4 p1 = *(const float4*)(xr + kb * 32 + 4);
            A[kb][0] = f2bf(p0.x); A[kb][1] = f2bf(p0.y);
            A[kb][2] = f2bf(p0.z); A[kb][3] = f2bf(p0.w);
            A[kb][4] = f2bf(p1.x); A[kb][5] = f2bf(p1.y);
            A[kb][6] = f2bf(p1.z); A[kb][7] = f2bf(p1.w);
        }

        #pragma unroll
        for (int ct = 0; ct < 4; ct++) {
            f32x4 aq = {bqv[ct], bqv[ct], bqv[ct], bqv[ct]};
            f32x4 ak = {bkv[ct], bkv[ct], bkv[ct], bkv[ct]};
            f32x4 av = {bvv[ct], bvv[ct], bvv[ct], bvv[ct]};
            aq = __builtin_amdgcn_mfma_f32_16x16x32_bf16(A[0], Bq[ct][0], aq, 0, 0, 0);
            aq = __builtin_amdgcn_mfma_f32_16x16x32_bf16(A[1], Bq[ct][1], aq, 0, 0, 0);
            ak = __builtin_amdgcn_mfma_f32_16x16x32_bf16(A[0], Bk[ct][0], ak, 0, 0, 0);
            ak = __builtin_amdgcn_mfma_f32_16x16x32_bf16(A[1], Bk[ct][1], ak, 0, 0, 0);
            av = __builtin_amdgcn_mfma_f32_16x16x32_bf16(A[0], Bv[ct][0], av, 0, 0, 0);
            av = __builtin_amdgcn_mfma_f32_16x16x32_bf16(A[1], Bv[ct][1], av, 0, 0, 0);
            #pragma unroll
            for (int i = 0; i < 4; i++) {
                long long off = (long long)(row0 + quad * 4 + i) * 64 + ct * 16 + m;
                q[off] = aq[i];
                k[off] = (_Float16)ak[i];
                v[off] = (_Float16)av[i];
            }
        }
    }
}

// ---------------------------------------------------------------------------
// per-dst histogram (for aggregate + dst-level scan)
// ---------------------------------------------------------------------------
__global__ __launch_bounds__(256) void hist_kernel(
    const int* __restrict__ e2e, int* __restrict__ counts)
{
    int m4 = (blockIdx.x * 256 + threadIdx.x) * 4;
    if (m4 < M_N) {
        int4 d = *(const int4*)(e2e + M_N + m4);
        atomicAdd(&counts[d.x], 1);
        atomicAdd(&counts[d.y], 1);
        atomicAdd(&counts[d.z], 1);
        atomicAdd(&counts[d.w], 1);
    }
}

// ---------------------------------------------------------------------------
// generic 2-level exclusive scan (chunk size SCAN_CHUNK)
// ---------------------------------------------------------------------------
__global__ __launch_bounds__(256) void scan1_kernel(
    const int* __restrict__ counts, int* __restrict__ cursor,
    int* __restrict__ blocksums, int len)
{
    __shared__ int s[256];
    const int t = threadIdx.x;
    const int base = blockIdx.x * SCAN_CHUNK + t * 8;

    int vals[8];
    int tot = 0;
    #pragma unroll
    for (int j = 0; j < 8; j++) {
        int idx = base + j;
        vals[j] = (idx < len) ? counts[idx] : 0;
        tot += vals[j];
    }
    s[t] = tot;
    __syncthreads();
    for (int off = 1; off < 256; off <<= 1) {
        int add = (t >= off) ? s[t - off] : 0;
        __syncthreads();
        s[t] += add;
        __syncthreads();
    }
    int excl = (t == 0) ? 0 : s[t - 1];
    if (t == 255) blocksums[blockIdx.x] = s[255];

    int run = excl;
    #pragma unroll
    for (int j = 0; j < 8; j++) {
        int idx = base + j;
        if (idx < len) cursor[idx] = run;
        run += vals[j];
    }
}

__global__ __launch_bounds__(256) void scan2_kernel(
    const int* __restrict__ blocksums, int* __restrict__ blockoff, int nb)
{
    __shared__ int s[256];
    const int t = threadIdx.x;
    s[t] = (t < nb) ? blocksums[t] : 0;
    __syncthreads();
    for (int off = 1; off < 256; off <<= 1) {
        int add = (t >= off) ? s[t - off] : 0;
        __syncthreads();
        s[t] += add;
        __syncthreads();
    }
    if (t < nb) blockoff[t] = (t == 0) ? 0 : s[t - 1];
}

// ---------------------------------------------------------------------------
// per-(bucket,chunk) histogram: bucket = dst>>7, one block per m-chunk.
// ---------------------------------------------------------------------------
__global__ __launch_bounds__(1024) void bhist_kernel(
    const int* __restrict__ e2e, int* __restrict__ bcnt)
{
    __shared__ int lc[NBUCK];
    const int c = blockIdx.x;
    for (int i = threadIdx.x; i < NBUCK; i += 1024) lc[i] = 0;
    __syncthreads();
    const int m0 = c * CH;
    for (int i = threadIdx.x * 4; i < CH; i += 1024 * 4) {
        int4 d = *(const int4*)(e2e + M_N + m0 + i);
        atomicAdd(&lc[d.x >> 7], 1);
        atomicAdd(&lc[d.y >> 7], 1);
        atomicAdd(&lc[d.z >> 7], 1);
        atomicAdd(&lc[d.w >> 7], 1);
    }
    __syncthreads();
    for (int i = threadIdx.x; i < NBUCK; i += 1024) bcnt[i * NCHUNK + c] = lc[i];
}

// ---------------------------------------------------------------------------
// scatter v2: full in-LDS counting sort of the chunk's pair indices by bucket,
// then emit in bucket order. Consecutive threads write consecutive global
// slots -> streaming coalesced writes, full L2 line combining.
// meta = (dst_low7 << 18) | src  (src < 2^18), bias converted to f16.
// ---------------------------------------------------------------------------
__global__ __launch_bounds__(1024) void scatter_bucket(
    const int* __restrict__ e2e, const float* __restrict__ bias,
    const int* __restrict__ bcur0, const int* __restrict__ boff2,
    int* __restrict__ meta, _Float16* __restrict__ bias_s)
{
    __shared__ unsigned short ord[CH];   // chunk-local index, sorted by bucket
    __shared__ int cnt[NBUCK];           // histogram, then running cursor
    __shared__ int lbase[NBUCK];         // local exclusive base per bucket
    __shared__ int gbase[NBUCK];         // global slot base per (bucket,chunk)
    __shared__ int s[1024];
    const int c = blockIdx.x;
    const int t = threadIdx.x;
    const int m0 = c * CH;

    for (int b = t; b < NBUCK; b += 1024) {
        cnt[b] = 0;
        int idx = b * NCHUNK + c;
        gbase[b] = bcur0[idx] + boff2[idx >> 11];
    }
    __syncthreads();

    // phase 1: bucket histogram (coalesced dst reads)
    for (int i = t * 4; i < CH; i += 4096) {
        int4 d = *(const int4*)(e2e + M_N + m0 + i);
        atomicAdd(&cnt[d.x >> 7], 1);
        atomicAdd(&cnt[d.y >> 7], 1);
        atomicAdd(&cnt[d.z >> 7], 1);
        atomicAdd(&cnt[d.w >> 7], 1);
    }
    __syncthreads();

    // phase 2: block-wide exclusive scan over NBUCK (2 elems / thread)
    int v0 = (2 * t     < NBUCK) ? cnt[2 * t]     : 0;
    int v1 = (2 * t + 1 < NBUCK) ? cnt[2 * t + 1] : 0;
    s[t] = v0 + v1;
    __syncthreads();
    for (int off = 1; off < 1024; off <<= 1) {
        int add = (t >= off) ? s[t - off] : 0;
        __syncthreads();
        s[t] += add;
        __syncthreads();
    }
    int excl = (t == 0) ? 0 : s[t - 1];
    if (2 * t     < NBUCK) lbase[2 * t]     = excl;
    if (2 * t + 1 < NBUCK) lbase[2 * t + 1] = excl + v0;
    __syncthreads();
    for (int b = t; b < NBUCK; b += 1024) cnt[b] = lbase[b];
    __syncthreads();

    // phase 3: rank each pair, scatter chunk-local index into ord (LDS only)
    for (int i = t; i < CH; i += 1024) {
        int dst = e2e[M_N + m0 + i];          // L2-warm
        int r = atomicAdd(&cnt[dst >> 7], 1);
        ord[r] = (unsigned short)i;
    }
    __syncthreads();

    // phase 4: emit in bucket order -> consecutive threads, consecutive slots
    for (int j = t; j < CH; j += 1024) {
        int i = ord[j];
        int m = m0 + i;
        int dst = e2e[M_N + m];               // L2-warm gather
        int src = e2e[m];                     // gather within 40KB window
        int b = dst >> 7;
        int slot = gbase[b] + (j - lbase[b]);
        meta[slot] = ((dst & 127) << 18) | src;

        float4 b0 = *(const float4*)(bias + (long long)m * 8);
        float4 b1 = *(const float4*)(bias + (long long)m * 8 + 4);
        f16x8 bb;
        bb[0] = (_Float16)b0.x; bb[1] = (_Float16)b0.y;
        bb[2] = (_Float16)b0.z; bb[3] = (_Float16)b0.w;
        bb[4] = (_Float16)b1.x; bb[5] = (_Float16)b1.y;
        bb[6] = (_Float16)b1.z; bb[7] = (_Float16)b1.w;
        *(f16x8*)(bias_s + (long long)slot * 8) = bb;
    }
}

// ---------------------------------------------------------------------------
// finish the sort within each bucket (128 dst values) entirely in LDS,
// permuting meta->sorted(src) and bias_s in place. Coalesced, L2/L3-warm.
// __syncthreads drains vmcnt(0) so all reads complete before in-place writes.
// ---------------------------------------------------------------------------
__global__ __launch_bounds__(256) void bucket_permute(
    const int* __restrict__ cursor, const int* __restrict__ boff,
    int* __restrict__ meta, _Float16* __restrict__ bias_s)
{
    __shared__ int smeta[SMAX];
    __shared__ int cnt[128];
    __shared__ int scn[128];
    const int b = blockIdx.x;
    const int t = threadIdx.x;
    const int d0 = b << 7;
    const int bs = cursor[d0] + boff[d0 >> 11];
    const int d1 = d0 + 128;
    const int be = (d1 < E_N) ? (cursor[d1] + boff[d1 >> 11]) : M_N;
    int n = be - bs;
    if (n > SMAX) n = SMAX;   // ~45 sigma; memory-safety clamp only

    if (t < 128) cnt[t] = 0;
    __syncthreads();
    #pragma unroll
    for (int r = 0; r < SMAX / 256; r++) {
        int i = t + r * 256;
        if (i < n) {
            int mm = meta[bs + i];
            smeta[i] = mm;
            atomicAdd(&cnt[mm >> 18], 1);
        }
    }
    __syncthreads();
    if (t < 128) scn[t] = cnt[t];
    __syncthreads();
    for (int off = 1; off < 128; off <<= 1) {
        int v = 0;
        if (t < 128 && t >= off) v = scn[t - off];
        __syncthreads();
        if (t < 128) scn[t] += v;
        __syncthreads();
    }
    if (t < 128) cnt[t] = scn[t] - cnt[t];   // exclusive base; cnt reused as cursor
    __syncthreads();

    int    pos[SMAX / 256];
    f16x8  bb[SMAX / 256];
    #pragma unroll
    for (int r = 0; r < SMAX / 256; r++) {
        int i = t + r * 256;
        if (i < n) {
            int mm = smeta[i];
            pos[r] = bs + atomicAdd(&cnt[mm >> 18], 1);
            bb[r]  = *(const f16x8*)(bias_s + (long long)(bs + i) * 8);
        }
    }
    __syncthreads();   // all reads drained (vmcnt 0) before any in-place write
    #pragma unroll
    for (int r = 0; r < SMAX / 256; r++) {
        int i = t + r * 256;
        if (i < n) {
            meta[pos[r]] = smeta[i] & 0x3FFFF;
            *(f16x8*)(bias_s + (long long)pos[r] * 8) = bb[r];
        }
    }
}

// ---------------------------------------------------------------------------
// aggregate: one wave per dst edge, 8 pairs in parallel per batch.
// Dot phase: lane = ps*8 + t (pair slot, head); accum phase: lane = h*8 + d.
// cursor is PRISTINE (start offset); end = start + counts[e].
// ---------------------------------------------------------------------------
__global__ __launch_bounds__(256) void aggregate_kernel(
    const _Float16* __restrict__ k, const _Float16* __restrict__ v,
    const _Float16* __restrict__ bias_s,
    const int* __restrict__ counts, const int* __restrict__ cursor,
    const int* __restrict__ blockoff,
    const int* __restrict__ sorted,
    float* __restrict__ qmsg)
{
    const int wid  = threadIdx.x >> 6;
    const int lane = threadIdx.x & 63;
    const int ps   = lane >> 3;
    const int t    = lane & 7;

    for (int e = blockIdx.x * 4 + wid; e < E_N; e += gridDim.x * 4) {
        float qv = qmsg[(long long)e * 64 + lane];

        float qs[8];
        #pragma unroll
        for (int j = 0; j < 8; j++) qs[j] = __shfl(qv, t * 8 + j, 64);

        int start = cursor[e] + blockoff[e >> 11];
        int cnt   = counts[e];
        int end   = start + cnt;

        float acc = 0.0f, wsum = 0.0f;
        for (int i = start; i < end; i += 8) {
            int idx = i + ps;
            bool valid = idx < end;
            int src = valid ? sorted[idx] : 0;
            float bs = valid ? (float)bias_s[(long long)idx * 8 + t] : 0.0f;

            f16x8 kk = *(const f16x8*)(k + (long long)src * 64 + t * 8);
            float dot = 0.0f;
            #pragma unroll
            for (int j = 0; j < 8; j++) dot = fmaf(qs[j], (float)kk[j], dot);

            float w = valid ? __expf(fmaf(dot, 0.35355339059327373f, bs)) : 0.0f;

            int   srcj[8];
            float wj[8];
            #pragma unroll
            for (int j = 0; j < 8; j++) {
                srcj[j] = __shfl(src, j * 8, 64);
                wj[j]   = __shfl(w, j * 8 + ps, 64);
            }
            #pragma unroll
            for (int j = 0; j < 8; j++) {
                float vv = (float)v[(long long)srcj[j] * 64 + lane];
                acc  += wj[j] * vv;
                wsum += wj[j];
            }
        }
        qmsg[(long long)e * 64 + lane] = acc / (wsum + 1e-16f);
    }
}

// ---------------------------------------------------------------------------
// out = msg @ Wo + bo via MFMA, in-place on d_out.
// ---------------------------------------------------------------------------
__global__ __launch_bounds__(256) void out_mfma(
    const float* __restrict__ Wo, const float* __restrict__ bo,
    float* __restrict__ out)
{
    const int w    = threadIdx.x >> 6;
    const int lane = threadIdx.x & 63;
    const int quad = lane >> 4;
    const int m    = lane & 15;

    bf16x8 B[4][2];
    float  bov[4];
    #pragma unroll
    for (int ct = 0; ct < 4; ct++) {
        int cc = ct * 16 + m;
        bov[ct] = bo[cc];
        #pragma unroll
        for (int kb = 0; kb < 2; kb++) {
            #pragma unroll
            for (int j = 0; j < 8; j++) {
                int kk = kb * 32 + quad * 8 + j;
                B[ct][kb][j] = f2bf(Wo[kk * 64 + cc]);
            }
        }
    }

    for (int row0 = blockIdx.x * 64 + w * 16; row0 < E_N; row0 += gridDim.x * 64) {
        const float* xr = out + (long long)(row0 + m) * 64 + quad * 8;
        bf16x8 A[2];
        #pragma unroll
        for (int kb = 0; kb < 2; kb++) {
            float4 p0 = *(const float4*)(xr + kb * 32);
            float4 p1 = *(const float4*)(xr + kb * 32 + 4);
            A[kb][0] = f2bf(p0.x); A[kb][1] = f2bf(p0.y);
            A[kb][2] = f2bf(p0.z); A[kb][3] = f2bf(p0.w);
            A[kb][4] = f2bf(p1.x); A[kb][5] = f2bf(p1.y);
            A[kb][6] = f2bf(p1.z); A[kb][7] = f2bf(p1.w);
        }

        f32x4 acc[4];
        #pragma unroll
        for (int ct = 0; ct < 4; ct++) {
            acc[ct] = (f32x4){bov[ct], bov[ct], bov[ct], bov[ct]};
            acc[ct] = __builtin_amdgcn_mfma_f32_16x16x32_bf16(A[0], B[ct][0], acc[ct], 0, 0, 0);
            acc[ct] = __builtin_amdgcn_mfma_f32_16x16x32_bf16(A[1], B[ct][1], acc[ct], 0, 0, 0);
        }
        #pragma unroll
        for (int ct = 0; ct < 4; ct++) {
            #pragma unroll
            for (int i = 0; i < 4; i++) {
                out[(long long)(row0 + quad * 4 + i) * 64 + ct * 16 + m] = acc[ct][i];
            }
        }
    }
}

extern "C" void kernel_launch(void* const* d_in, const int* in_sizes, int n_in,
                              void* d_out, int out_size, void* d_ws, size_t ws_size,
                              hipStream_t stream) {
    const float* x    = (const float*)d_in[0];
    const int*   e2e  = (const int*)  d_in[1];
    const float* bias = (const float*)d_in[2];
    const float* Wq   = (const float*)d_in[3];
    const float* bq   = (const float*)d_in[4];
    const float* Wk   = (const float*)d_in[5];
    const float* bk   = (const float*)d_in[6];
    const float* Wv   = (const float*)d_in[7];
    const float* bv   = (const float*)d_in[8];
    const float* Wo   = (const float*)d_in[9];
    const float* bo   = (const float*)d_in[10];
    float* out = (float*)d_out;   // q buffer -> msg buffer -> final out (in place)

    // ws: k_h[12.8M f16] | v_h[12.8M f16] | counts | cursor | bsum | boff |
    //     sorted[3.2M int] | bias_s[25.6M f16] | bcnt[BLEN] | bcur0[BLEN] |
    //     bsum2[256] | boff2[256]   (total ~121 MB)
    _Float16* kh     = (_Float16*)d_ws;
    _Float16* vh     = kh + (long long)E_N * 64;
    int*      counts = (int*)(vh + (long long)E_N * 64);
    int*      cursor = counts + E_N;
    int*      bsum   = cursor + E_N;
    int*      boff   = bsum + 256;
    int*      sorted = boff + 256;
    _Float16* bias_s = (_Float16*)(sorted + M_N);
    int*      bcnt   = (int*)(bias_s + (long long)M_N * 8);
    int*      bcur0  = bcnt + BLEN;
    int*      bsum2  = bcur0 + BLEN;
    int*      boff2  = bsum2 + 256;

    hipMemsetAsync(counts, 0, (size_t)E_N * sizeof(int), stream);

    qkv_mfma<<<640, 256, 0, stream>>>(x, Wq, bq, Wk, bk, Wv, bv, out, kh, vh);

    // dst-level histogram + scan (pristine; consumed by aggregate + permute)
    hist_kernel<<<M_N / 1024, 256, 0, stream>>>(e2e, counts);
    scan1_kernel<<<NB1, 256, 0, stream>>>(counts, cursor, bsum, E_N);
    scan2_kernel<<<1, 256, 0, stream>>>(bsum, boff, NB1);

    // (bucket,chunk) histogram + scan -> exact disjoint slot ranges per block
    bhist_kernel<<<NCHUNK, 1024, 0, stream>>>(e2e, bcnt);
    scan1_kernel<<<NB2, 256, 0, stream>>>(bcnt, bcur0, bsum2, BLEN);
    scan2_kernel<<<1, 256, 0, stream>>>(bsum2, boff2, NB2);

    // deterministic in-LDS chunk sort -> streaming coalesced scatter,
    // then finish dst-order within each bucket in LDS
    scatter_bucket<<<NCHUNK, 1024, 0, stream>>>(e2e, bias, bcur0, boff2,
                                                sorted, bias_s);
    bucket_permute<<<NBUCK, 256, 0, stream>>>(cursor, boff, sorted, bias_s);

    aggregate_kernel<<<8192, 256, 0, stream>>>(kh, vh, bias_s, counts, cursor,
                                               boff, sorted, out);

    out_mfma<<<640, 256, 0, stream>>>(Wo, bo, out);
}

// Round 3
// 728.685 us; speedup vs baseline: 1.0540x; 1.0234x over previous
//
#include <hip/hip_runtime.h>

#define E_N 200000
#define M_N 3200000
#define SCAN_CHUNK 2048
#define NB1 98          // ceil(E_N / SCAN_CHUNK)

// bucket sort geometry
#define NBUCK 1563      // ceil(E_N / 128), 128 dst per bucket
#define NCHUNK 256      // m-chunks (one block each, 1/CU)
#define CH 12500        // pairs per chunk: NCHUNK*CH == M_N
#define BLEN (NBUCK * NCHUNK)   // 400128
#define NB2 196         // ceil(BLEN / SCAN_CHUNK)
#define NP 13           // pairs per thread: ceil(CH/1024)
#define WW 1792         // emit window width (ranks)
#define NH 7            // ceil(CH/WW)
#define SMAX 4096       // max records per bucket handled in LDS (mean 2048, ~45 sigma)

typedef __attribute__((ext_vector_type(8))) short bf16x8;      // MFMA A/B frag
typedef __attribute__((ext_vector_type(4))) float f32x4;       // MFMA C/D frag
typedef __attribute__((ext_vector_type(8))) _Float16 f16x8;    // 16B of f16

// fp32 -> bf16 (round to nearest even), raw short
__device__ __forceinline__ short f2bf(float f) {
    union { float f; unsigned u; } x; x.f = f;
    unsigned r = x.u + 0x7fffu + ((x.u >> 16) & 1u);
    return (short)(r >> 16);
}

// ---------------------------------------------------------------------------
// qkv via MFMA: q (fp32, to d_out) and k/v (f16) = x @ W + b.
// One wave per 16-row stripe; block = 4 waves = 64 rows/iter. E_N % 64 == 0.
// ---------------------------------------------------------------------------
__global__ __launch_bounds__(256) void qkv_mfma(
    const float* __restrict__ x,
    const float* __restrict__ Wq, const float* __restrict__ bq,
    const float* __restrict__ Wk, const float* __restrict__ bk,
    const float* __restrict__ Wv, const float* __restrict__ bv,
    float* __restrict__ q, _Float16* __restrict__ k, _Float16* __restrict__ v)
{
    const int w    = threadIdx.x >> 6;
    const int lane = threadIdx.x & 63;
    const int quad = lane >> 4;
    const int m    = lane & 15;

    bf16x8 Bq[4][2], Bk[4][2], Bv[4][2];
    float  bqv[4], bkv[4], bvv[4];
    #pragma unroll
    for (int ct = 0; ct < 4; ct++) {
        int cc = ct * 16 + m;
        bqv[ct] = bq[cc]; bkv[ct] = bk[cc]; bvv[ct] = bv[cc];
        #pragma unroll
        for (int kb = 0; kb < 2; kb++) {
            #pragma unroll
            for (int j = 0; j < 8; j++) {
                int kk = kb * 32 + quad * 8 + j;
                Bq[ct][kb][j] = f2bf(Wq[kk * 64 + cc]);
                Bk[ct][kb][j] = f2bf(Wk[kk * 64 + cc]);
                Bv[ct][kb][j] = f2bf(Wv[kk * 64 + cc]);
            }
        }
    }

    for (int row0 = blockIdx.x * 64 + w * 16; row0 < E_N; row0 += gridDim.x * 64) {
        const float* xr = x + (long long)(row0 + m) * 64 + quad * 8;
        bf16x8 A[2];
        #pragma unroll
        for (int kb = 0; kb < 2; kb++) {
            float4 p0 = *(const float4*)(xr + kb * 32);
            float4 p1 = *(const float4*)(xr + kb * 32 + 4);
            A[kb][0] = f2bf(p0.x); A[kb][1] = f2bf(p0.y);
            A[kb][2] = f2bf(p0.z); A[kb][3] = f2bf(p0.w);
            A[kb][4] = f2bf(p1.x); A[kb][5] = f2bf(p1.y);
            A[kb][6] = f2bf(p1.z); A[kb][7] = f2bf(p1.w);
        }

        #pragma unroll
        for (int ct = 0; ct < 4; ct++) {
            f32x4 aq = {bqv[ct], bqv[ct], bqv[ct], bqv[ct]};
            f32x4 ak = {bkv[ct], bkv[ct], bkv[ct], bkv[ct]};
            f32x4 av = {bvv[ct], bvv[ct], bvv[ct], bvv[ct]};
            aq = __builtin_amdgcn_mfma_f32_16x16x32_bf16(A[0], Bq[ct][0], aq, 0, 0, 0);
            aq = __builtin_amdgcn_mfma_f32_16x16x32_bf16(A[1], Bq[ct][1], aq, 0, 0, 0);
            ak = __builtin_amdgcn_mfma_f32_16x16x32_bf16(A[0], Bk[ct][0], ak, 0, 0, 0);
            ak = __builtin_amdgcn_mfma_f32_16x16x32_bf16(A[1], Bk[ct][1], ak, 0, 0, 0);
            av = __builtin_amdgcn_mfma_f32_16x16x32_bf16(A[0], Bv[ct][0], av, 0, 0, 0);
            av = __builtin_amdgcn_mfma_f32_16x16x32_bf16(A[1], Bv[ct][1], av, 0, 0, 0);
            #pragma unroll
            for (int i = 0; i < 4; i++) {
                long long off = (long long)(row0 + quad * 4 + i) * 64 + ct * 16 + m;
                q[off] = aq[i];
                k[off] = (_Float16)ak[i];
                v[off] = (_Float16)av[i];
            }
        }
    }
}

// ---------------------------------------------------------------------------
// per-dst histogram (for aggregate + dst-level scan)
// ---------------------------------------------------------------------------
__global__ __launch_bounds__(256) void hist_kernel(
    const int* __restrict__ e2e, int* __restrict__ counts)
{
    int m4 = (blockIdx.x * 256 + threadIdx.x) * 4;
    if (m4 < M_N) {
        int4 d = *(const int4*)(e2e + M_N + m4);
        atomicAdd(&counts[d.x], 1);
        atomicAdd(&counts[d.y], 1);
        atomicAdd(&counts[d.z], 1);
        atomicAdd(&counts[d.w], 1);
    }
}

// ---------------------------------------------------------------------------
// generic 2-level exclusive scan (chunk size SCAN_CHUNK)
// ---------------------------------------------------------------------------
__global__ __launch_bounds__(256) void scan1_kernel(
    const int* __restrict__ counts, int* __restrict__ cursor,
    int* __restrict__ blocksums, int len)
{
    __shared__ int s[256];
    const int t = threadIdx.x;
    const int base = blockIdx.x * SCAN_CHUNK + t * 8;

    int vals[8];
    int tot = 0;
    #pragma unroll
    for (int j = 0; j < 8; j++) {
        int idx = base + j;
        vals[j] = (idx < len) ? counts[idx] : 0;
        tot += vals[j];
    }
    s[t] = tot;
    __syncthreads();
    for (int off = 1; off < 256; off <<= 1) {
        int add = (t >= off) ? s[t - off] : 0;
        __syncthreads();
        s[t] += add;
        __syncthreads();
    }
    int excl = (t == 0) ? 0 : s[t - 1];
    if (t == 255) blocksums[blockIdx.x] = s[255];

    int run = excl;
    #pragma unroll
    for (int j = 0; j < 8; j++) {
        int idx = base + j;
        if (idx < len) cursor[idx] = run;
        run += vals[j];
    }
}

__global__ __launch_bounds__(256) void scan2_kernel(
    const int* __restrict__ blocksums, int* __restrict__ blockoff, int nb)
{
    __shared__ int s[256];
    const int t = threadIdx.x;
    s[t] = (t < nb) ? blocksums[t] : 0;
    __syncthreads();
    for (int off = 1; off < 256; off <<= 1) {
        int add = (t >= off) ? s[t - off] : 0;
        __syncthreads();
        s[t] += add;
        __syncthreads();
    }
    if (t < nb) blockoff[t] = (t == 0) ? 0 : s[t - 1];
}

// ---------------------------------------------------------------------------
// per-(bucket,chunk) histogram: bucket = dst>>7, one block per m-chunk.
// ---------------------------------------------------------------------------
__global__ __launch_bounds__(1024) void bhist_kernel(
    const int* __restrict__ e2e, int* __restrict__ bcnt)
{
    __shared__ int lc[NBUCK];
    const int c = blockIdx.x;
    for (int i = threadIdx.x; i < NBUCK; i += 1024) lc[i] = 0;
    __syncthreads();
    const int m0 = c * CH;
    for (int i = threadIdx.x * 4; i < CH; i += 1024 * 4) {
        int4 d = *(const int4*)(e2e + M_N + m0 + i);
        atomicAdd(&lc[d.x >> 7], 1);
        atomicAdd(&lc[d.y >> 7], 1);
        atomicAdd(&lc[d.z >> 7], 1);
        atomicAdd(&lc[d.w >> 7], 1);
    }
    __syncthreads();
    for (int i = threadIdx.x; i < NBUCK; i += 1024) bcnt[i * NCHUNK + c] = lc[i];
}

// ---------------------------------------------------------------------------
// scatter v3: payload held in REGISTERS across the sort (no gather anywhere).
// Coalesced load -> LDS histogram -> block scan -> LDS atomic rank ->
// windowed LDS stage -> coalesced streaming emit in bucket order.
// meta = (dst_low7 << 18) | src  (src < 2^18), bias converted to f16.
// pk = (bucket << 14) | rank  (bucket < 2048, rank < 16384), -1 = invalid.
// ---------------------------------------------------------------------------
__global__ __launch_bounds__(1024) void scatter_bucket(
    const int* __restrict__ e2e, const float* __restrict__ bias,
    const int* __restrict__ bcur0, const int* __restrict__ boff2,
    int* __restrict__ meta, _Float16* __restrict__ bias_s)
{
    __shared__ int cnt[NBUCK];            // histogram -> running cursor
    __shared__ int lbase[NBUCK];          // chunk-local exclusive base
    __shared__ int gbase[NBUCK];          // global slot base per (bucket,chunk)
    __shared__ int s[1024];
    __shared__ int            stage_meta[WW];
    __shared__ f16x8          stage_bias[WW];
    __shared__ unsigned short stage_bk[WW];

    const int c = blockIdx.x;
    const int t = threadIdx.x;
    const int m0 = c * CH;

    for (int b = t; b < NBUCK; b += 1024) {
        cnt[b] = 0;
        int idx = b * NCHUNK + c;
        gbase[b] = bcur0[idx] + boff2[idx >> 11];
    }
    __syncthreads();

    // phase 1: coalesced loads; payload -> registers; bucket histogram
    int   mt[NP];
    int   pk[NP];
    f16x8 bb[NP];
    #pragma unroll
    for (int r = 0; r < NP; r++) {
        int i = t + r * 1024;
        pk[r] = -1;
        if (i < CH) {
            int m = m0 + i;
            int dst = e2e[M_N + m];
            int src = e2e[m];
            int b = dst >> 7;
            pk[r] = b << 14;                  // rank filled in phase 3
            mt[r] = ((dst & 127) << 18) | src;
            float4 b0 = *(const float4*)(bias + (long long)m * 8);
            float4 b1 = *(const float4*)(bias + (long long)m * 8 + 4);
            f16x8 xx;
            xx[0] = (_Float16)b0.x; xx[1] = (_Float16)b0.y;
            xx[2] = (_Float16)b0.z; xx[3] = (_Float16)b0.w;
            xx[4] = (_Float16)b1.x; xx[5] = (_Float16)b1.y;
            xx[6] = (_Float16)b1.z; xx[7] = (_Float16)b1.w;
            bb[r] = xx;
            atomicAdd(&cnt[b], 1);
        }
    }
    __syncthreads();

    // phase 2: block-wide exclusive scan over NBUCK (2 elems / thread)
    int v0 = (2 * t     < NBUCK) ? cnt[2 * t]     : 0;
    int v1 = (2 * t + 1 < NBUCK) ? cnt[2 * t + 1] : 0;
    s[t] = v0 + v1;
    __syncthreads();
    for (int off = 1; off < 1024; off <<= 1) {
        int add = (t >= off) ? s[t - off] : 0;
        __syncthreads();
        s[t] += add;
        __syncthreads();
    }
    int excl = (t == 0) ? 0 : s[t - 1];
    if (2 * t     < NBUCK) lbase[2 * t]     = excl;
    if (2 * t + 1 < NBUCK) lbase[2 * t + 1] = excl + v0;
    __syncthreads();
    for (int b = t; b < NBUCK; b += 1024) cnt[b] = lbase[b];
    __syncthreads();

    // phase 3: claim rank per held pair (content deterministic per bucket-set)
    #pragma unroll
    for (int r = 0; r < NP; r++) {
        if (pk[r] >= 0) {
            int b = pk[r] >> 14;
            int rk = atomicAdd(&cnt[b], 1);
            pk[r] = (b << 14) | rk;
        }
    }
    __syncthreads();

    // phase 4: windowed stage + coalesced emit (regs -> LDS -> global stream)
    for (int h = 0; h < NH; h++) {
        int lo = h * WW;
        int hi = lo + WW; if (hi > CH) hi = CH;
        #pragma unroll
        for (int r = 0; r < NP; r++) {
            if (pk[r] >= 0) {
                int rk = pk[r] & 16383;
                if (rk >= lo && rk < hi) {
                    int p = rk - lo;
                    stage_meta[p] = mt[r];
                    stage_bias[p] = bb[r];
                    stage_bk[p]   = (unsigned short)(pk[r] >> 14);
                }
            }
        }
        __syncthreads();
        for (int j = lo + t; j < hi; j += 1024) {
            int p = j - lo;
            int b = stage_bk[p];
            int slot = gbase[b] + (j - lbase[b]);
            meta[slot] = stage_meta[p];
            *(f16x8*)(bias_s + (long long)slot * 8) = stage_bias[p];
        }
        __syncthreads();
    }
}

// ---------------------------------------------------------------------------
// finish the sort within each bucket (128 dst values) entirely in LDS,
// permuting meta->sorted(src) and bias_s in place. Coalesced, L2/L3-warm.
// __syncthreads drains vmcnt(0) so all reads complete before in-place writes.
// ---------------------------------------------------------------------------
__global__ __launch_bounds__(256) void bucket_permute(
    const int* __restrict__ cursor, const int* __restrict__ boff,
    int* __restrict__ meta, _Float16* __restrict__ bias_s)
{
    __shared__ int smeta[SMAX];
    __shared__ int cnt[128];
    __shared__ int scn[128];
    const int b = blockIdx.x;
    const int t = threadIdx.x;
    const int d0 = b << 7;
    const int bs = cursor[d0] + boff[d0 >> 11];
    const int d1 = d0 + 128;
    const int be = (d1 < E_N) ? (cursor[d1] + boff[d1 >> 11]) : M_N;
    int n = be - bs;
    if (n > SMAX) n = SMAX;   // ~45 sigma; memory-safety clamp only

    if (t < 128) cnt[t] = 0;
    __syncthreads();
    #pragma unroll
    for (int r = 0; r < SMAX / 256; r++) {
        int i = t + r * 256;
        if (i < n) {
            int mm = meta[bs + i];
            smeta[i] = mm;
            atomicAdd(&cnt[mm >> 18], 1);
        }
    }
    __syncthreads();
    if (t < 128) scn[t] = cnt[t];
    __syncthreads();
    for (int off = 1; off < 128; off <<= 1) {
        int v = 0;
        if (t < 128 && t >= off) v = scn[t - off];
        __syncthreads();
        if (t < 128) scn[t] += v;
        __syncthreads();
    }
    if (t < 128) cnt[t] = scn[t] - cnt[t];   // exclusive base; cnt reused as cursor
    __syncthreads();

    int    pos[SMAX / 256];
    f16x8  bb[SMAX / 256];
    #pragma unroll
    for (int r = 0; r < SMAX / 256; r++) {
        int i = t + r * 256;
        if (i < n) {
            int mm = smeta[i];
            pos[r] = bs + atomicAdd(&cnt[mm >> 18], 1);
            bb[r]  = *(const f16x8*)(bias_s + (long long)(bs + i) * 8);
        }
    }
    __syncthreads();   // all reads drained (vmcnt 0) before any in-place write
    #pragma unroll
    for (int r = 0; r < SMAX / 256; r++) {
        int i = t + r * 256;
        if (i < n) {
            meta[pos[r]] = smeta[i] & 0x3FFFF;
            *(f16x8*)(bias_s + (long long)pos[r] * 8) = bb[r];
        }
    }
}

// ---------------------------------------------------------------------------
// aggregate: one wave per dst edge, 8 pairs in parallel per batch.
// Dot phase: lane = ps*8 + t (pair slot, head); accum phase: lane = h*8 + d.
// cursor is PRISTINE (start offset); end = start + counts[e].
// ---------------------------------------------------------------------------
__global__ __launch_bounds__(256) void aggregate_kernel(
    const _Float16* __restrict__ k, const _Float16* __restrict__ v,
    const _Float16* __restrict__ bias_s,
    const int* __restrict__ counts, const int* __restrict__ cursor,
    const int* __restrict__ blockoff,
    const int* __restrict__ sorted,
    float* __restrict__ qmsg)
{
    const int wid  = threadIdx.x >> 6;
    const int lane = threadIdx.x & 63;
    const int ps   = lane >> 3;
    const int t    = lane & 7;

    for (int e = blockIdx.x * 4 + wid; e < E_N; e += gridDim.x * 4) {
        float qv = qmsg[(long long)e * 64 + lane];

        float qs[8];
        #pragma unroll
        for (int j = 0; j < 8; j++) qs[j] = __shfl(qv, t * 8 + j, 64);

        int start = cursor[e] + blockoff[e >> 11];
        int cnt   = counts[e];
        int end   = start + cnt;

        float acc = 0.0f, wsum = 0.0f;
        for (int i = start; i < end; i += 8) {
            int idx = i + ps;
            bool valid = idx < end;
            int src = valid ? sorted[idx] : 0;
            float bs = valid ? (float)bias_s[(long long)idx * 8 + t] : 0.0f;

            f16x8 kk = *(const f16x8*)(k + (long long)src * 64 + t * 8);
            float dot = 0.0f;
            #pragma unroll
            for (int j = 0; j < 8; j++) dot = fmaf(qs[j], (float)kk[j], dot);

            float w = valid ? __expf(fmaf(dot, 0.35355339059327373f, bs)) : 0.0f;

            int   srcj[8];
            float wj[8];
            #pragma unroll
            for (int j = 0; j < 8; j++) {
                srcj[j] = __shfl(src, j * 8, 64);
                wj[j]   = __shfl(w, j * 8 + ps, 64);
            }
            #pragma unroll
            for (int j = 0; j < 8; j++) {
                float vv = (float)v[(long long)srcj[j] * 64 + lane];
                acc  += wj[j] * vv;
                wsum += wj[j];
            }
        }
        qmsg[(long long)e * 64 + lane] = acc / (wsum + 1e-16f);
    }
}

// ---------------------------------------------------------------------------
// out = msg @ Wo + bo via MFMA, in-place on d_out.
// ---------------------------------------------------------------------------
__global__ __launch_bounds__(256) void out_mfma(
    const float* __restrict__ Wo, const float* __restrict__ bo,
    float* __restrict__ out)
{
    const int w    = threadIdx.x >> 6;
    const int lane = threadIdx.x & 63;
    const int quad = lane >> 4;
    const int m    = lane & 15;

    bf16x8 B[4][2];
    float  bov[4];
    #pragma unroll
    for (int ct = 0; ct < 4; ct++) {
        int cc = ct * 16 + m;
        bov[ct] = bo[cc];
        #pragma unroll
        for (int kb = 0; kb < 2; kb++) {
            #pragma unroll
            for (int j = 0; j < 8; j++) {
                int kk = kb * 32 + quad * 8 + j;
                B[ct][kb][j] = f2bf(Wo[kk * 64 + cc]);
            }
        }
    }

    for (int row0 = blockIdx.x * 64 + w * 16; row0 < E_N; row0 += gridDim.x * 64) {
        const float* xr = out + (long long)(row0 + m) * 64 + quad * 8;
        bf16x8 A[2];
        #pragma unroll
        for (int kb = 0; kb < 2; kb++) {
            float4 p0 = *(const float4*)(xr + kb * 32);
            float4 p1 = *(const float4*)(xr + kb * 32 + 4);
            A[kb][0] = f2bf(p0.x); A[kb][1] = f2bf(p0.y);
            A[kb][2] = f2bf(p0.z); A[kb][3] = f2bf(p0.w);
            A[kb][4] = f2bf(p1.x); A[kb][5] = f2bf(p1.y);
            A[kb][6] = f2bf(p1.z); A[kb][7] = f2bf(p1.w);
        }

        f32x4 acc[4];
        #pragma unroll
        for (int ct = 0; ct < 4; ct++) {
            acc[ct] = (f32x4){bov[ct], bov[ct], bov[ct], bov[ct]};
            acc[ct] = __builtin_amdgcn_mfma_f32_16x16x32_bf16(A[0], B[ct][0], acc[ct], 0, 0, 0);
            acc[ct] = __builtin_amdgcn_mfma_f32_16x16x32_bf16(A[1], B[ct][1], acc[ct], 0, 0, 0);
        }
        #pragma unroll
        for (int ct = 0; ct < 4; ct++) {
            #pragma unroll
            for (int i = 0; i < 4; i++) {
                out[(long long)(row0 + quad * 4 + i) * 64 + ct * 16 + m] = acc[ct][i];
            }
        }
    }
}

extern "C" void kernel_launch(void* const* d_in, const int* in_sizes, int n_in,
                              void* d_out, int out_size, void* d_ws, size_t ws_size,
                              hipStream_t stream) {
    const float* x    = (const float*)d_in[0];
    const int*   e2e  = (const int*)  d_in[1];
    const float* bias = (const float*)d_in[2];
    const float* Wq   = (const float*)d_in[3];
    const float* bq   = (const float*)d_in[4];
    const float* Wk   = (const float*)d_in[5];
    const float* bk   = (const float*)d_in[6];
    const float* Wv   = (const float*)d_in[7];
    const float* bv   = (const float*)d_in[8];
    const float* Wo   = (const float*)d_in[9];
    const float* bo   = (const float*)d_in[10];
    float* out = (float*)d_out;   // q buffer -> msg buffer -> final out (in place)

    // ws: k_h[12.8M f16] | v_h[12.8M f16] | counts | cursor | bsum | boff |
    //     sorted[3.2M int] | bias_s[25.6M f16] | bcnt[BLEN] | bcur0[BLEN] |
    //     bsum2[256] | boff2[256]   (total ~120 MB)
    _Float16* kh     = (_Float16*)d_ws;
    _Float16* vh     = kh + (long long)E_N * 64;
    int*      counts = (int*)(vh + (long long)E_N * 64);
    int*      cursor = counts + E_N;
    int*      bsum   = cursor + E_N;
    int*      boff   = bsum + 256;
    int*      sorted = boff + 256;
    _Float16* bias_s = (_Float16*)(sorted + M_N);
    int*      bcnt   = (int*)(bias_s + (long long)M_N * 8);
    int*      bcur0  = bcnt + BLEN;
    int*      bsum2  = bcur0 + BLEN;
    int*      boff2  = bsum2 + 256;

    hipMemsetAsync(counts, 0, (size_t)E_N * sizeof(int), stream);

    qkv_mfma<<<640, 256, 0, stream>>>(x, Wq, bq, Wk, bk, Wv, bv, out, kh, vh);

    // dst-level histogram + scan (pristine; consumed by aggregate + permute)
    hist_kernel<<<M_N / 1024, 256, 0, stream>>>(e2e, counts);
    scan1_kernel<<<NB1, 256, 0, stream>>>(counts, cursor, bsum, E_N);
    scan2_kernel<<<1, 256, 0, stream>>>(bsum, boff, NB1);

    // (bucket,chunk) histogram + scan -> exact disjoint slot ranges per block
    bhist_kernel<<<NCHUNK, 1024, 0, stream>>>(e2e, bcnt);
    scan1_kernel<<<NB2, 256, 0, stream>>>(bcnt, bcur0, bsum2, BLEN);
    scan2_kernel<<<1, 256, 0, stream>>>(bsum2, boff2, NB2);

    // payload-in-registers counting sort -> streaming coalesced scatter,
    // then finish dst-order within each bucket in LDS
    scatter_bucket<<<NCHUNK, 1024, 0, stream>>>(e2e, bias, bcur0, boff2,
                                                sorted, bias_s);
    bucket_permute<<<NBUCK, 256, 0, stream>>>(cursor, boff, sorted, bias_s);

    aggregate_kernel<<<8192, 256, 0, stream>>>(kh, vh, bias_s, counts, cursor,
                                               boff, sorted, out);

    out_mfma<<<640, 256, 0, stream>>>(Wo, bo, out);
}

// Round 4
// 663.776 us; speedup vs baseline: 1.1570x; 1.0978x over previous
//
#include <hip/hip_runtime.h>

#define E_N 200000
#define M_N 3200000
#define SCAN_CHUNK 2048
#define NB1 98          // ceil(E_N / SCAN_CHUNK)

// bucket sort geometry (256 dst per bucket)
#define NBUCK 782       // ceil(E_N / 256)
#define NCHUNK 1000     // m-chunks (one block each)
#define CH 3200         // pairs per chunk: NCHUNK*CH == M_N
#define BLEN (NBUCK * NCHUNK)   // 782000
#define NB2 382         // ceil(BLEN / SCAN_CHUNK)
#define NP 4            // pairs per thread: ceil(CH/1024)
#define SMAX 8192       // max records per bucket in LDS (mean 4096, ~64 sigma)

typedef __attribute__((ext_vector_type(8))) short bf16x8;      // MFMA A/B frag
typedef __attribute__((ext_vector_type(4))) float f32x4;       // MFMA C/D frag
typedef __attribute__((ext_vector_type(8))) _Float16 f16x8;    // 16B of f16

// fp32 -> bf16 (round to nearest even), raw short
__device__ __forceinline__ short f2bf(float f) {
    union { float f; unsigned u; } x; x.f = f;
    unsigned r = x.u + 0x7fffu + ((x.u >> 16) & 1u);
    return (short)(r >> 16);
}

// ---------------------------------------------------------------------------
// qkv via MFMA: q (fp32, to d_out) and k/v (f16) = x @ W + b.
// One wave per 16-row stripe; block = 4 waves = 64 rows/iter. E_N % 64 == 0.
// ---------------------------------------------------------------------------
__global__ __launch_bounds__(256) void qkv_mfma(
    const float* __restrict__ x,
    const float* __restrict__ Wq, const float* __restrict__ bq,
    const float* __restrict__ Wk, const float* __restrict__ bk,
    const float* __restrict__ Wv, const float* __restrict__ bv,
    float* __restrict__ q, _Float16* __restrict__ k, _Float16* __restrict__ v)
{
    const int w    = threadIdx.x >> 6;
    const int lane = threadIdx.x & 63;
    const int quad = lane >> 4;
    const int m    = lane & 15;

    bf16x8 Bq[4][2], Bk[4][2], Bv[4][2];
    float  bqv[4], bkv[4], bvv[4];
    #pragma unroll
    for (int ct = 0; ct < 4; ct++) {
        int cc = ct * 16 + m;
        bqv[ct] = bq[cc]; bkv[ct] = bk[cc]; bvv[ct] = bv[cc];
        #pragma unroll
        for (int kb = 0; kb < 2; kb++) {
            #pragma unroll
            for (int j = 0; j < 8; j++) {
                int kk = kb * 32 + quad * 8 + j;
                Bq[ct][kb][j] = f2bf(Wq[kk * 64 + cc]);
                Bk[ct][kb][j] = f2bf(Wk[kk * 64 + cc]);
                Bv[ct][kb][j] = f2bf(Wv[kk * 64 + cc]);
            }
        }
    }

    for (int row0 = blockIdx.x * 64 + w * 16; row0 < E_N; row0 += gridDim.x * 64) {
        const float* xr = x + (long long)(row0 + m) * 64 + quad * 8;
        bf16x8 A[2];
        #pragma unroll
        for (int kb = 0; kb < 2; kb++) {
            float4 p0 = *(const float4*)(xr + kb * 32);
            float4 p1 = *(const float4*)(xr + kb * 32 + 4);
            A[kb][0] = f2bf(p0.x); A[kb][1] = f2bf(p0.y);
            A[kb][2] = f2bf(p0.z); A[kb][3] = f2bf(p0.w);
            A[kb][4] = f2bf(p1.x); A[kb][5] = f2bf(p1.y);
            A[kb][6] = f2bf(p1.z); A[kb][7] = f2bf(p1.w);
        }

        #pragma unroll
        for (int ct = 0; ct < 4; ct++) {
            f32x4 aq = {bqv[ct], bqv[ct], bqv[ct], bqv[ct]};
            f32x4 ak = {bkv[ct], bkv[ct], bkv[ct], bkv[ct]};
            f32x4 av = {bvv[ct], bvv[ct], bvv[ct], bvv[ct]};
            aq = __builtin_amdgcn_mfma_f32_16x16x32_bf16(A[0], Bq[ct][0], aq, 0, 0, 0);
            aq = __builtin_amdgcn_mfma_f32_16x16x32_bf16(A[1], Bq[ct][1], aq, 0, 0, 0);
            ak = __builtin_amdgcn_mfma_f32_16x16x32_bf16(A[0], Bk[ct][0], ak, 0, 0, 0);
            ak = __builtin_amdgcn_mfma_f32_16x16x32_bf16(A[1], Bk[ct][1], ak, 0, 0, 0);
            av = __builtin_amdgcn_mfma_f32_16x16x32_bf16(A[0], Bv[ct][0], av, 0, 0, 0);
            av = __builtin_amdgcn_mfma_f32_16x16x32_bf16(A[1], Bv[ct][1], av, 0, 0, 0);
            #pragma unroll
            for (int i = 0; i < 4; i++) {
                long long off = (long long)(row0 + quad * 4 + i) * 64 + ct * 16 + m;
                q[off] = aq[i];
                k[off] = (_Float16)ak[i];
                v[off] = (_Float16)av[i];
            }
        }
    }
}

// ---------------------------------------------------------------------------
// per-dst histogram (for aggregate + dst-level scan)
// ---------------------------------------------------------------------------
__global__ __launch_bounds__(256) void hist_kernel(
    const int* __restrict__ e2e, int* __restrict__ counts)
{
    int m4 = (blockIdx.x * 256 + threadIdx.x) * 4;
    if (m4 < M_N) {
        int4 d = *(const int4*)(e2e + M_N + m4);
        atomicAdd(&counts[d.x], 1);
        atomicAdd(&counts[d.y], 1);
        atomicAdd(&counts[d.z], 1);
        atomicAdd(&counts[d.w], 1);
    }
}

// ---------------------------------------------------------------------------
// generic 2-level exclusive scan (chunk size SCAN_CHUNK). In-place safe
// (cursor may alias counts: each thread reads its 8 before writing them).
// ---------------------------------------------------------------------------
__global__ __launch_bounds__(256) void scan1_kernel(
    const int* __restrict__ counts, int* __restrict__ cursor,
    int* __restrict__ blocksums, int len)
{
    __shared__ int s[256];
    const int t = threadIdx.x;
    const int base = blockIdx.x * SCAN_CHUNK + t * 8;

    int vals[8];
    int tot = 0;
    #pragma unroll
    for (int j = 0; j < 8; j++) {
        int idx = base + j;
        vals[j] = (idx < len) ? counts[idx] : 0;
        tot += vals[j];
    }
    s[t] = tot;
    __syncthreads();
    for (int off = 1; off < 256; off <<= 1) {
        int add = (t >= off) ? s[t - off] : 0;
        __syncthreads();
        s[t] += add;
        __syncthreads();
    }
    int excl = (t == 0) ? 0 : s[t - 1];
    if (t == 255) blocksums[blockIdx.x] = s[255];

    int run = excl;
    #pragma unroll
    for (int j = 0; j < 8; j++) {
        int idx = base + j;
        if (idx < len) cursor[idx] = run;
        run += vals[j];
    }
}

// exclusive scan of up to 1024 block sums (4/thread at 256 threads)
__global__ __launch_bounds__(256) void scan2_kernel(
    const int* __restrict__ blocksums, int* __restrict__ blockoff, int nb)
{
    __shared__ int s[256];
    const int t = threadIdx.x;
    int vals[4];
    int tot = 0;
    #pragma unroll
    for (int u = 0; u < 4; u++) {
        int idx = t * 4 + u;
        vals[u] = (idx < nb) ? blocksums[idx] : 0;
        tot += vals[u];
    }
    s[t] = tot;
    __syncthreads();
    for (int off = 1; off < 256; off <<= 1) {
        int add = (t >= off) ? s[t - off] : 0;
        __syncthreads();
        s[t] += add;
        __syncthreads();
    }
    int run = (t == 0) ? 0 : s[t - 1];
    #pragma unroll
    for (int u = 0; u < 4; u++) {
        int idx = t * 4 + u;
        if (idx < nb) blockoff[idx] = run;
        run += vals[u];
    }
}

// ---------------------------------------------------------------------------
// per-(bucket,chunk) histogram: bucket = dst>>8, one block per m-chunk.
// ---------------------------------------------------------------------------
__global__ __launch_bounds__(1024) void bhist_kernel(
    const int* __restrict__ e2e, int* __restrict__ bcnt)
{
    __shared__ int lc[NBUCK];
    const int c = blockIdx.x;
    for (int i = threadIdx.x; i < NBUCK; i += 1024) lc[i] = 0;
    __syncthreads();
    const int m0 = c * CH;
    for (int i = threadIdx.x * 4; i < CH; i += 4096) {
        int4 d = *(const int4*)(e2e + M_N + m0 + i);
        atomicAdd(&lc[d.x >> 8], 1);
        atomicAdd(&lc[d.y >> 8], 1);
        atomicAdd(&lc[d.z >> 8], 1);
        atomicAdd(&lc[d.w >> 8], 1);
    }
    __syncthreads();
    for (int i = threadIdx.x; i < NBUCK; i += 1024) bcnt[i * NCHUNK + c] = lc[i];
}

// ---------------------------------------------------------------------------
// scatter v4: NP=4 payload in registers (24 VGPR - no spill), whole chunk
// staged in ONE LDS window. Coalesced load -> LDS hist -> scan -> rank ->
// stage bias (pool) + bk -> coalesced emit -> re-stage meta (same pool) ->
// coalesced emit. All global traffic is coalesced streams.
// meta = (dst_low8 << 18) | src  (src < 2^18).
// pk = (bucket << 12) | j  (bucket < 782, j < 3200), -1 = invalid.
// ---------------------------------------------------------------------------
__global__ __launch_bounds__(1024, 4) void scatter_bucket(
    const int* __restrict__ e2e, const float* __restrict__ bias,
    const int* __restrict__ bcur0, const int* __restrict__ boff2,
    int* __restrict__ meta, _Float16* __restrict__ bias_s)
{
    __shared__ int gbase[NBUCK];                       // slot base minus lbase
    __shared__ unsigned short bk[CH];                  // bucket per rank j
    __shared__ char pool[CH * 16] __attribute__((aligned(16)));   // 50 KB union
    int*   cnt     = (int*)pool;                       // [NBUCK] phases 1-3
    int*   s       = (int*)(pool + 4096);              // [1024]  phase 2
    f16x8* stage_b = (f16x8*)pool;                     // [CH]    phase 4a
    int*   stage_m = (int*)pool;                       // [CH]    phase 4b

    const int c = blockIdx.x;
    const int t = threadIdx.x;
    const int m0 = c * CH;

    for (int b = t; b < NBUCK; b += 1024) {
        cnt[b] = 0;
        int idx = b * NCHUNK + c;
        gbase[b] = bcur0[idx] + boff2[idx >> 11];
    }
    __syncthreads();

    // phase 1: coalesced loads; payload -> registers; bucket histogram
    int   mt[NP];
    int   pk[NP];
    f16x8 bb[NP];
    #pragma unroll
    for (int r = 0; r < NP; r++) {
        int i = t + r * 1024;
        pk[r] = -1;
        if (i < CH) {
            int m = m0 + i;
            int dst = e2e[M_N + m];
            int src = e2e[m];
            int b = dst >> 8;
            pk[r] = b << 12;
            mt[r] = ((dst & 255) << 18) | src;
            float4 b0 = *(const float4*)(bias + (long long)m * 8);
            float4 b1 = *(const float4*)(bias + (long long)m * 8 + 4);
            f16x8 xx;
            xx[0] = (_Float16)b0.x; xx[1] = (_Float16)b0.y;
            xx[2] = (_Float16)b0.z; xx[3] = (_Float16)b0.w;
            xx[4] = (_Float16)b1.x; xx[5] = (_Float16)b1.y;
            xx[6] = (_Float16)b1.z; xx[7] = (_Float16)b1.w;
            bb[r] = xx;
            atomicAdd(&cnt[b], 1);
        }
    }
    __syncthreads();

    // phase 2: exclusive scan over NBUCK buckets; fold lbase into gbase
    int v = (t < NBUCK) ? cnt[t] : 0;
    s[t] = v;
    __syncthreads();
    for (int off = 1; off < 1024; off <<= 1) {
        int add = (t >= off) ? s[t - off] : 0;
        __syncthreads();
        s[t] += add;
        __syncthreads();
    }
    if (t < NBUCK) {
        int excl = (t == 0) ? 0 : s[t - 1];
        gbase[t] -= excl;          // slot = gbase[b] + j
        cnt[t] = excl;             // running cursor (global chunk rank j)
    }
    __syncthreads();

    // phase 3: claim rank j per held pair
    #pragma unroll
    for (int r = 0; r < NP; r++) {
        if (pk[r] >= 0) {
            int b = pk[r] >> 12;
            int j = atomicAdd(&cnt[b], 1);
            pk[r] = (b << 12) | j;
        }
    }
    __syncthreads();   // cnt dead; pool reused as stage

    // phase 4a: stage bias + bk by rank, emit coalesced in rank order
    #pragma unroll
    for (int r = 0; r < NP; r++) {
        if (pk[r] >= 0) {
            int j = pk[r] & 4095;
            stage_b[j] = bb[r];
            bk[j] = (unsigned short)(pk[r] >> 12);
        }
    }
    __syncthreads();
    for (int j = t; j < CH; j += 1024) {
        int slot = gbase[bk[j]] + j;
        *(f16x8*)(bias_s + (long long)slot * 8) = stage_b[j];
    }
    __syncthreads();

    // phase 4b: re-stage meta in same pool (bk persists), emit coalesced
    #pragma unroll
    for (int r = 0; r < NP; r++) {
        if (pk[r] >= 0) stage_m[pk[r] & 4095] = mt[r];
    }
    __syncthreads();
    for (int j = t; j < CH; j += 1024) {
        meta[gbase[bk[j]] + j] = stage_m[j];
    }
}

// ---------------------------------------------------------------------------
// finish the sort within each bucket (256 dst values) entirely in LDS,
// permuting meta->sorted(src) and bias_s in place. Coalesced, L2/L3-warm.
// __syncthreads drains vmcnt(0) so all reads complete before in-place writes.
// ---------------------------------------------------------------------------
__global__ __launch_bounds__(512, 2) void bucket_permute(
    const int* __restrict__ cursor, const int* __restrict__ boff,
    int* __restrict__ meta, _Float16* __restrict__ bias_s)
{
    __shared__ int smeta[SMAX];
    __shared__ int cnt[256];
    __shared__ int scn[256];
    const int b = blockIdx.x;
    const int t = threadIdx.x;
    const int d0 = b << 8;
    const int bs = cursor[d0] + boff[d0 >> 11];
    const int d1 = d0 + 256;
    const int be = (d1 < E_N) ? (cursor[d1] + boff[d1 >> 11]) : M_N;
    int n = be - bs;
    if (n > SMAX) n = SMAX;   // ~64 sigma; memory-safety clamp only

    if (t < 256) cnt[t] = 0;
    __syncthreads();
    #pragma unroll
    for (int r = 0; r < SMAX / 512; r++) {
        int i = t + r * 512;
        if (i < n) {
            int mm = meta[bs + i];
            smeta[i] = mm;
            atomicAdd(&cnt[mm >> 18], 1);
        }
    }
    __syncthreads();
    if (t < 256) scn[t] = cnt[t];
    __syncthreads();
    for (int off = 1; off < 256; off <<= 1) {
        int v = 0;
        if (t < 256 && t >= off) v = scn[t - off];
        __syncthreads();
        if (t < 256) scn[t] += v;
        __syncthreads();
    }
    if (t < 256) cnt[t] = scn[t] - cnt[t];   // exclusive base -> running cursor
    __syncthreads();

    int    pos[SMAX / 512];
    f16x8  bb[SMAX / 512];
    #pragma unroll
    for (int r = 0; r < SMAX / 512; r++) {
        int i = t + r * 512;
        if (i < n) {
            int mm = smeta[i];
            pos[r] = bs + atomicAdd(&cnt[mm >> 18], 1);
            bb[r]  = *(const f16x8*)(bias_s + (long long)(bs + i) * 8);
        }
    }
    __syncthreads();   // all reads drained (vmcnt 0) before any in-place write
    #pragma unroll
    for (int r = 0; r < SMAX / 512; r++) {
        int i = t + r * 512;
        if (i < n) {
            meta[pos[r]] = smeta[i] & 0x3FFFF;
            *(f16x8*)(bias_s + (long long)pos[r] * 8) = bb[r];
        }
    }
}

// ---------------------------------------------------------------------------
// aggregate: one wave per dst edge, 8 pairs in parallel per batch.
// Dot phase: lane = ps*8 + t (pair slot, head); accum phase: lane = h*8 + d.
// cursor is PRISTINE (start offset); end = start + counts[e].
// ---------------------------------------------------------------------------
__global__ __launch_bounds__(256) void aggregate_kernel(
    const _Float16* __restrict__ k, const _Float16* __restrict__ v,
    const _Float16* __restrict__ bias_s,
    const int* __restrict__ counts, const int* __restrict__ cursor,
    const int* __restrict__ blockoff,
    const int* __restrict__ sorted,
    float* __restrict__ qmsg)
{
    const int wid  = threadIdx.x >> 6;
    const int lane = threadIdx.x & 63;
    const int ps   = lane >> 3;
    const int t    = lane & 7;

    for (int e = blockIdx.x * 4 + wid; e < E_N; e += gridDim.x * 4) {
        float qv = qmsg[(long long)e * 64 + lane];

        float qs[8];
        #pragma unroll
        for (int j = 0; j < 8; j++) qs[j] = __shfl(qv, t * 8 + j, 64);

        int start = cursor[e] + blockoff[e >> 11];
        int cnt   = counts[e];
        int end   = start + cnt;

        float acc = 0.0f, wsum = 0.0f;
        for (int i = start; i < end; i += 8) {
            int idx = i + ps;
            bool valid = idx < end;
            int src = valid ? sorted[idx] : 0;
            float bs = valid ? (float)bias_s[(long long)idx * 8 + t] : 0.0f;

            f16x8 kk = *(const f16x8*)(k + (long long)src * 64 + t * 8);
            float dot = 0.0f;
            #pragma unroll
            for (int j = 0; j < 8; j++) dot = fmaf(qs[j], (float)kk[j], dot);

            float w = valid ? __expf(fmaf(dot, 0.35355339059327373f, bs)) : 0.0f;

            int   srcj[8];
            float wj[8];
            #pragma unroll
            for (int j = 0; j < 8; j++) {
                srcj[j] = __shfl(src, j * 8, 64);
                wj[j]   = __shfl(w, j * 8 + ps, 64);
            }
            #pragma unroll
            for (int j = 0; j < 8; j++) {
                float vv = (float)v[(long long)srcj[j] * 64 + lane];
                acc  += wj[j] * vv;
                wsum += wj[j];
            }
        }
        qmsg[(long long)e * 64 + lane] = acc / (wsum + 1e-16f);
    }
}

// ---------------------------------------------------------------------------
// out = msg @ Wo + bo via MFMA, in-place on d_out.
// ---------------------------------------------------------------------------
__global__ __launch_bounds__(256) void out_mfma(
    const float* __restrict__ Wo, const float* __restrict__ bo,
    float* __restrict__ out)
{
    const int w    = threadIdx.x >> 6;
    const int lane = threadIdx.x & 63;
    const int quad = lane >> 4;
    const int m    = lane & 15;

    bf16x8 B[4][2];
    float  bov[4];
    #pragma unroll
    for (int ct = 0; ct < 4; ct++) {
        int cc = ct * 16 + m;
        bov[ct] = bo[cc];
        #pragma unroll
        for (int kb = 0; kb < 2; kb++) {
            #pragma unroll
            for (int j = 0; j < 8; j++) {
                int kk = kb * 32 + quad * 8 + j;
                B[ct][kb][j] = f2bf(Wo[kk * 64 + cc]);
            }
        }
    }

    for (int row0 = blockIdx.x * 64 + w * 16; row0 < E_N; row0 += gridDim.x * 64) {
        const float* xr = out + (long long)(row0 + m) * 64 + quad * 8;
        bf16x8 A[2];
        #pragma unroll
        for (int kb = 0; kb < 2; kb++) {
            float4 p0 = *(const float4*)(xr + kb * 32);
            float4 p1 = *(const float4*)(xr + kb * 32 + 4);
            A[kb][0] = f2bf(p0.x); A[kb][1] = f2bf(p0.y);
            A[kb][2] = f2bf(p0.z); A[kb][3] = f2bf(p0.w);
            A[kb][4] = f2bf(p1.x); A[kb][5] = f2bf(p1.y);
            A[kb][6] = f2bf(p1.z); A[kb][7] = f2bf(p1.w);
        }

        f32x4 acc[4];
        #pragma unroll
        for (int ct = 0; ct < 4; ct++) {
            acc[ct] = (f32x4){bov[ct], bov[ct], bov[ct], bov[ct]};
            acc[ct] = __builtin_amdgcn_mfma_f32_16x16x32_bf16(A[0], B[ct][0], acc[ct], 0, 0, 0);
            acc[ct] = __builtin_amdgcn_mfma_f32_16x16x32_bf16(A[1], B[ct][1], acc[ct], 0, 0, 0);
        }
        #pragma unroll
        for (int ct = 0; ct < 4; ct++) {
            #pragma unroll
            for (int i = 0; i < 4; i++) {
                out[(long long)(row0 + quad * 4 + i) * 64 + ct * 16 + m] = acc[ct][i];
            }
        }
    }
}

extern "C" void kernel_launch(void* const* d_in, const int* in_sizes, int n_in,
                              void* d_out, int out_size, void* d_ws, size_t ws_size,
                              hipStream_t stream) {
    const float* x    = (const float*)d_in[0];
    const int*   e2e  = (const int*)  d_in[1];
    const float* bias = (const float*)d_in[2];
    const float* Wq   = (const float*)d_in[3];
    const float* bq   = (const float*)d_in[4];
    const float* Wk   = (const float*)d_in[5];
    const float* bk   = (const float*)d_in[6];
    const float* Wv   = (const float*)d_in[7];
    const float* bv   = (const float*)d_in[8];
    const float* Wo   = (const float*)d_in[9];
    const float* bo   = (const float*)d_in[10];
    float* out = (float*)d_out;   // q buffer -> msg buffer -> final out (in place)

    // ws: k_h[12.8M f16] | v_h[12.8M f16] | counts | cursor | bsum | boff |
    //     sorted[3.2M int] | bias_s[25.6M f16] | bcnt[BLEN, scanned in place] |
    //     bsum2[512] | boff2[512]   (total ~120 MB)
    _Float16* kh     = (_Float16*)d_ws;
    _Float16* vh     = kh + (long long)E_N * 64;
    int*      counts = (int*)(vh + (long long)E_N * 64);
    int*      cursor = counts + E_N;
    int*      bsum   = cursor + E_N;
    int*      boff   = bsum + 512;
    int*      sorted = boff + 512;
    _Float16* bias_s = (_Float16*)(sorted + M_N);
    int*      bcnt   = (int*)(bias_s + (long long)M_N * 8);
    int*      bsum2  = bcnt + BLEN;
    int*      boff2  = bsum2 + 512;

    hipMemsetAsync(counts, 0, (size_t)E_N * sizeof(int), stream);

    qkv_mfma<<<640, 256, 0, stream>>>(x, Wq, bq, Wk, bk, Wv, bv, out, kh, vh);

    // dst-level histogram + scan (pristine; consumed by aggregate + permute)
    hist_kernel<<<M_N / 1024, 256, 0, stream>>>(e2e, counts);
    scan1_kernel<<<NB1, 256, 0, stream>>>(counts, cursor, bsum, E_N);
    scan2_kernel<<<1, 256, 0, stream>>>(bsum, boff, NB1);

    // (bucket,chunk) histogram + in-place scan -> disjoint slot ranges
    bhist_kernel<<<NCHUNK, 1024, 0, stream>>>(e2e, bcnt);
    scan1_kernel<<<NB2, 256, 0, stream>>>(bcnt, bcnt, bsum2, BLEN);
    scan2_kernel<<<1, 256, 0, stream>>>(bsum2, boff2, NB2);

    // register-payload counting sort, single-window LDS stage, streaming emit
    scatter_bucket<<<NCHUNK, 1024, 0, stream>>>(e2e, bias, bcnt, boff2,
                                                sorted, bias_s);
    bucket_permute<<<NBUCK, 512, 0, stream>>>(cursor, boff, sorted, bias_s);

    aggregate_kernel<<<8192, 256, 0, stream>>>(kh, vh, bias_s, counts, cursor,
                                               boff, sorted, out);

    out_mfma<<<640, 256, 0, stream>>>(Wo, bo, out);
}

// Round 6
// 652.108 us; speedup vs baseline: 1.1777x; 1.0179x over previous
//
#include <hip/hip_runtime.h>

#define E_N 200000
#define M_N 3200000
#define SCAN_CHUNK 2048
#define NB1 98          // ceil(E_N / SCAN_CHUNK)

// bucket sort geometry (256 dst per bucket)
#define NBUCK 782       // ceil(E_N / 256)
#define NCHUNK 1000     // m-chunks (one block each)
#define CH 3200         // pairs per chunk: NCHUNK*CH == M_N
#define BLEN (NBUCK * NCHUNK)   // 782000
#define NB2 382         // ceil(BLEN / SCAN_CHUNK)
#define NP 4            // pairs per thread: ceil(CH/1024)
#define SMAX 8192       // max records per bucket in LDS (mean 4096, ~64 sigma)

typedef __attribute__((ext_vector_type(8))) short bf16x8;      // MFMA A/B frag
typedef __attribute__((ext_vector_type(4))) float f32x4;       // MFMA C/D frag
typedef __attribute__((ext_vector_type(8))) _Float16 f16x8;    // 16B of f16

// fp32 -> bf16 (round to nearest even), raw short
__device__ __forceinline__ short f2bf(float f) {
    union { float f; unsigned u; } x; x.f = f;
    unsigned r = x.u + 0x7fffu + ((x.u >> 16) & 1u);
    return (short)(r >> 16);
}

// ---------------------------------------------------------------------------
// qkv via MFMA: q (fp32, to d_out) and k/v (f16) = x @ W + b.
// One wave per 16-row stripe; block = 4 waves = 64 rows/iter. E_N % 64 == 0.
// ---------------------------------------------------------------------------
__global__ __launch_bounds__(256) void qkv_mfma(
    const float* __restrict__ x,
    const float* __restrict__ Wq, const float* __restrict__ bq,
    const float* __restrict__ Wk, const float* __restrict__ bk,
    const float* __restrict__ Wv, const float* __restrict__ bv,
    float* __restrict__ q, _Float16* __restrict__ k, _Float16* __restrict__ v)
{
    const int w    = threadIdx.x >> 6;
    const int lane = threadIdx.x & 63;
    const int quad = lane >> 4;
    const int m    = lane & 15;

    bf16x8 Bq[4][2], Bk[4][2], Bv[4][2];
    float  bqv[4], bkv[4], bvv[4];
    #pragma unroll
    for (int ct = 0; ct < 4; ct++) {
        int cc = ct * 16 + m;
        bqv[ct] = bq[cc]; bkv[ct] = bk[cc]; bvv[ct] = bv[cc];
        #pragma unroll
        for (int kb = 0; kb < 2; kb++) {
            #pragma unroll
            for (int j = 0; j < 8; j++) {
                int kk = kb * 32 + quad * 8 + j;
                Bq[ct][kb][j] = f2bf(Wq[kk * 64 + cc]);
                Bk[ct][kb][j] = f2bf(Wk[kk * 64 + cc]);
                Bv[ct][kb][j] = f2bf(Wv[kk * 64 + cc]);
            }
        }
    }

    for (int row0 = blockIdx.x * 64 + w * 16; row0 < E_N; row0 += gridDim.x * 64) {
        const float* xr = x + (long long)(row0 + m) * 64 + quad * 8;
        bf16x8 A[2];
        #pragma unroll
        for (int kb = 0; kb < 2; kb++) {
            float4 p0 = *(const float4*)(xr + kb * 32);
            float4 p1 = *(const float4*)(xr + kb * 32 + 4);
            A[kb][0] = f2bf(p0.x); A[kb][1] = f2bf(p0.y);
            A[kb][2] = f2bf(p0.z); A[kb][3] = f2bf(p0.w);
            A[kb][4] = f2bf(p1.x); A[kb][5] = f2bf(p1.y);
            A[kb][6] = f2bf(p1.z); A[kb][7] = f2bf(p1.w);
        }

        #pragma unroll
        for (int ct = 0; ct < 4; ct++) {
            f32x4 aq = {bqv[ct], bqv[ct], bqv[ct], bqv[ct]};
            f32x4 ak = {bkv[ct], bkv[ct], bkv[ct], bkv[ct]};
            f32x4 av = {bvv[ct], bvv[ct], bvv[ct], bvv[ct]};
            aq = __builtin_amdgcn_mfma_f32_16x16x32_bf16(A[0], Bq[ct][0], aq, 0, 0, 0);
            aq = __builtin_amdgcn_mfma_f32_16x16x32_bf16(A[1], Bq[ct][1], aq, 0, 0, 0);
            ak = __builtin_amdgcn_mfma_f32_16x16x32_bf16(A[0], Bk[ct][0], ak, 0, 0, 0);
            ak = __builtin_amdgcn_mfma_f32_16x16x32_bf16(A[1], Bk[ct][1], ak, 0, 0, 0);
            av = __builtin_amdgcn_mfma_f32_16x16x32_bf16(A[0], Bv[ct][0], av, 0, 0, 0);
            av = __builtin_amdgcn_mfma_f32_16x16x32_bf16(A[1], Bv[ct][1], av, 0, 0, 0);
            #pragma unroll
            for (int i = 0; i < 4; i++) {
                long long off = (long long)(row0 + quad * 4 + i) * 64 + ct * 16 + m;
                q[off] = aq[i];
                k[off] = (_Float16)ak[i];
                v[off] = (_Float16)av[i];
            }
        }
    }
}

// ---------------------------------------------------------------------------
// per-dst histogram (for aggregate + dst-level scan)
// ---------------------------------------------------------------------------
__global__ __launch_bounds__(256) void hist_kernel(
    const int* __restrict__ e2e, int* __restrict__ counts)
{
    int m4 = (blockIdx.x * 256 + threadIdx.x) * 4;
    if (m4 < M_N) {
        int4 d = *(const int4*)(e2e + M_N + m4);
        atomicAdd(&counts[d.x], 1);
        atomicAdd(&counts[d.y], 1);
        atomicAdd(&counts[d.z], 1);
        atomicAdd(&counts[d.w], 1);
    }
}

// ---------------------------------------------------------------------------
// generic 2-level exclusive scan (chunk size SCAN_CHUNK). In-place safe
// (cursor may alias counts: each thread reads its 8 before writing them).
// ---------------------------------------------------------------------------
__global__ __launch_bounds__(256) void scan1_kernel(
    const int* __restrict__ counts, int* __restrict__ cursor,
    int* __restrict__ blocksums, int len)
{
    __shared__ int s[256];
    const int t = threadIdx.x;
    const int base = blockIdx.x * SCAN_CHUNK + t * 8;

    int vals[8];
    int tot = 0;
    #pragma unroll
    for (int j = 0; j < 8; j++) {
        int idx = base + j;
        vals[j] = (idx < len) ? counts[idx] : 0;
        tot += vals[j];
    }
    s[t] = tot;
    __syncthreads();
    for (int off = 1; off < 256; off <<= 1) {
        int add = (t >= off) ? s[t - off] : 0;
        __syncthreads();
        s[t] += add;
        __syncthreads();
    }
    int excl = (t == 0) ? 0 : s[t - 1];
    if (t == 255) blocksums[blockIdx.x] = s[255];

    int run = excl;
    #pragma unroll
    for (int j = 0; j < 8; j++) {
        int idx = base + j;
        if (idx < len) cursor[idx] = run;
        run += vals[j];
    }
}

// exclusive scan of up to 1024 block sums (4/thread at 256 threads)
__global__ __launch_bounds__(256) void scan2_kernel(
    const int* __restrict__ blocksums, int* __restrict__ blockoff, int nb)
{
    __shared__ int s[256];
    const int t = threadIdx.x;
    int vals[4];
    int tot = 0;
    #pragma unroll
    for (int u = 0; u < 4; u++) {
        int idx = t * 4 + u;
        vals[u] = (idx < nb) ? blocksums[idx] : 0;
        tot += vals[u];
    }
    s[t] = tot;
    __syncthreads();
    for (int off = 1; off < 256; off <<= 1) {
        int add = (t >= off) ? s[t - off] : 0;
        __syncthreads();
        s[t] += add;
        __syncthreads();
    }
    int run = (t == 0) ? 0 : s[t - 1];
    #pragma unroll
    for (int u = 0; u < 4; u++) {
        int idx = t * 4 + u;
        if (idx < nb) blockoff[idx] = run;
        run += vals[u];
    }
}

// ---------------------------------------------------------------------------
// per-(bucket,chunk) histogram: bucket = dst>>8, one block per m-chunk.
// ---------------------------------------------------------------------------
__global__ __launch_bounds__(1024) void bhist_kernel(
    const int* __restrict__ e2e, int* __restrict__ bcnt)
{
    __shared__ int lc[NBUCK];
    const int c = blockIdx.x;
    for (int i = threadIdx.x; i < NBUCK; i += 1024) lc[i] = 0;
    __syncthreads();
    const int m0 = c * CH;
    for (int i = threadIdx.x * 4; i < CH; i += 4096) {
        int4 d = *(const int4*)(e2e + M_N + m0 + i);
        atomicAdd(&lc[d.x >> 8], 1);
        atomicAdd(&lc[d.y >> 8], 1);
        atomicAdd(&lc[d.z >> 8], 1);
        atomicAdd(&lc[d.w >> 8], 1);
    }
    __syncthreads();
    for (int i = threadIdx.x; i < NBUCK; i += 1024) bcnt[i * NCHUNK + c] = lc[i];
}

// ---------------------------------------------------------------------------
// scatter v4: NP=4 payload in registers (24 VGPR - no spill), whole chunk
// staged in ONE LDS window. Coalesced load -> LDS hist -> scan -> rank ->
// stage bias (pool) + bk -> coalesced emit -> re-stage meta (same pool) ->
// coalesced emit. All global traffic is coalesced streams.
// meta = (dst_low8 << 18) | src  (src < 2^18).
// pk = (bucket << 12) | j  (bucket < 782, j < 3200), -1 = invalid.
// ---------------------------------------------------------------------------
__global__ __launch_bounds__(1024, 4) void scatter_bucket(
    const int* __restrict__ e2e, const float* __restrict__ bias,
    const int* __restrict__ bcur0, const int* __restrict__ boff2,
    int* __restrict__ meta, _Float16* __restrict__ bias_s)
{
    __shared__ int gbase[NBUCK];                       // slot base minus lbase
    __shared__ unsigned short bk[CH];                  // bucket per rank j
    __shared__ char pool[CH * 16] __attribute__((aligned(16)));   // 50 KB union
    int*   cnt     = (int*)pool;                       // [NBUCK] phases 1-3
    int*   s       = (int*)(pool + 4096);              // [1024]  phase 2
    f16x8* stage_b = (f16x8*)pool;                     // [CH]    phase 4a
    int*   stage_m = (int*)pool;                       // [CH]    phase 4b

    const int c = blockIdx.x;
    const int t = threadIdx.x;
    const int m0 = c * CH;

    for (int b = t; b < NBUCK; b += 1024) {
        cnt[b] = 0;
        int idx = b * NCHUNK + c;
        gbase[b] = bcur0[idx] + boff2[idx >> 11];
    }
    __syncthreads();

    // phase 1: coalesced loads; payload -> registers; bucket histogram
    int   mt[NP];
    int   pk[NP];
    f16x8 bb[NP];
    #pragma unroll
    for (int r = 0; r < NP; r++) {
        int i = t + r * 1024;
        pk[r] = -1;
        if (i < CH) {
            int m = m0 + i;
            int dst = e2e[M_N + m];
            int src = e2e[m];
            int b = dst >> 8;
            pk[r] = b << 12;
            mt[r] = ((dst & 255) << 18) | src;
            float4 b0 = *(const float4*)(bias + (long long)m * 8);
            float4 b1 = *(const float4*)(bias + (long long)m * 8 + 4);
            f16x8 xx;
            xx[0] = (_Float16)b0.x; xx[1] = (_Float16)b0.y;
            xx[2] = (_Float16)b0.z; xx[3] = (_Float16)b0.w;
            xx[4] = (_Float16)b1.x; xx[5] = (_Float16)b1.y;
            xx[6] = (_Float16)b1.z; xx[7] = (_Float16)b1.w;
            bb[r] = xx;
            atomicAdd(&cnt[b], 1);
        }
    }
    __syncthreads();

    // phase 2: exclusive scan over NBUCK buckets; fold lbase into gbase
    int v = (t < NBUCK) ? cnt[t] : 0;
    s[t] = v;
    __syncthreads();
    for (int off = 1; off < 1024; off <<= 1) {
        int add = (t >= off) ? s[t - off] : 0;
        __syncthreads();
        s[t] += add;
        __syncthreads();
    }
    if (t < NBUCK) {
        int excl = (t == 0) ? 0 : s[t - 1];
        gbase[t] -= excl;          // slot = gbase[b] + j
        cnt[t] = excl;             // running cursor (global chunk rank j)
    }
    __syncthreads();

    // phase 3: claim rank j per held pair
    #pragma unroll
    for (int r = 0; r < NP; r++) {
        if (pk[r] >= 0) {
            int b = pk[r] >> 12;
            int j = atomicAdd(&cnt[b], 1);
            pk[r] = (b << 12) | j;
        }
    }
    __syncthreads();   // cnt dead; pool reused as stage

    // phase 4a: stage bias + bk by rank, emit coalesced in rank order
    #pragma unroll
    for (int r = 0; r < NP; r++) {
        if (pk[r] >= 0) {
            int j = pk[r] & 4095;
            stage_b[j] = bb[r];
            bk[j] = (unsigned short)(pk[r] >> 12);
        }
    }
    __syncthreads();
    for (int j = t; j < CH; j += 1024) {
        int slot = gbase[bk[j]] + j;
        *(f16x8*)(bias_s + (long long)slot * 8) = stage_b[j];
    }
    __syncthreads();

    // phase 4b: re-stage meta in same pool (bk persists), emit coalesced
    #pragma unroll
    for (int r = 0; r < NP; r++) {
        if (pk[r] >= 0) stage_m[pk[r] & 4095] = mt[r];
    }
    __syncthreads();
    for (int j = t; j < CH; j += 1024) {
        meta[gbase[bk[j]] + j] = stage_m[j];
    }
}

// ---------------------------------------------------------------------------
// finish the sort within each bucket (256 dst values) entirely in LDS,
// permuting meta->sorted(src) and bias_s in place. Coalesced, L2/L3-warm.
// __syncthreads drains vmcnt(0) so all reads complete before in-place writes.
// ---------------------------------------------------------------------------
__global__ __launch_bounds__(512, 2) void bucket_permute(
    const int* __restrict__ cursor, const int* __restrict__ boff,
    int* __restrict__ meta, _Float16* __restrict__ bias_s)
{
    __shared__ int smeta[SMAX];
    __shared__ int cnt[256];
    __shared__ int scn[256];
    const int b = blockIdx.x;
    const int t = threadIdx.x;
    const int d0 = b << 8;
    const int bs = cursor[d0] + boff[d0 >> 11];
    const int d1 = d0 + 256;
    const int be = (d1 < E_N) ? (cursor[d1] + boff[d1 >> 11]) : M_N;
    int n = be - bs;
    if (n > SMAX) n = SMAX;   // ~64 sigma; memory-safety clamp only

    if (t < 256) cnt[t] = 0;
    __syncthreads();
    #pragma unroll
    for (int r = 0; r < SMAX / 512; r++) {
        int i = t + r * 512;
        if (i < n) {
            int mm = meta[bs + i];
            smeta[i] = mm;
            atomicAdd(&cnt[mm >> 18], 1);
        }
    }
    __syncthreads();
    if (t < 256) scn[t] = cnt[t];
    __syncthreads();
    for (int off = 1; off < 256; off <<= 1) {
        int v = 0;
        if (t < 256 && t >= off) v = scn[t - off];
        __syncthreads();
        if (t < 256) scn[t] += v;
        __syncthreads();
    }
    if (t < 256) cnt[t] = scn[t] - cnt[t];   // exclusive base -> running cursor
    __syncthreads();

    int    pos[SMAX / 512];
    f16x8  bb[SMAX / 512];
    #pragma unroll
    for (int r = 0; r < SMAX / 512; r++) {
        int i = t + r * 512;
        if (i < n) {
            int mm = smeta[i];
            pos[r] = bs + atomicAdd(&cnt[mm >> 18], 1);
            bb[r]  = *(const f16x8*)(bias_s + (long long)(bs + i) * 8);
        }
    }
    __syncthreads();   // all reads drained (vmcnt 0) before any in-place write
    #pragma unroll
    for (int r = 0; r < SMAX / 512; r++) {
        int i = t + r * 512;
        if (i < n) {
            meta[pos[r]] = smeta[i] & 0x3FFFF;
            *(f16x8*)(bias_s + (long long)pos[r] * 8) = bb[r];
        }
    }
}

// ---------------------------------------------------------------------------
// aggregate v2: lane (ps,t) owns pair slot ps, head t. Shuffle-free inner
// loop: per pair the lane loads its OWN 16B k and v slices, accumulates a
// private 8-wide partial for head t; cross-slot reduce is one 3-stage
// shfl_xor butterfly per dst. Unroll 2 sub-batches for latency ILP.
// cursor is PRISTINE (start offset); end = start + counts[e].
// ---------------------------------------------------------------------------
__global__ __launch_bounds__(256) void aggregate_kernel(
    const _Float16* __restrict__ k, const _Float16* __restrict__ v,
    const _Float16* __restrict__ bias_s,
    const int* __restrict__ counts, const int* __restrict__ cursor,
    const int* __restrict__ blockoff,
    const int* __restrict__ sorted,
    float* __restrict__ qmsg)
{
    const int wid  = threadIdx.x >> 6;
    const int lane = threadIdx.x & 63;
    const int ps   = lane >> 3;   // pair slot 0..7
    const int t    = lane & 7;    // head 0..7

    for (int e = blockIdx.x * 4 + wid; e < E_N; e += gridDim.x * 4) {
        float qv = qmsg[(long long)e * 64 + lane];
        float qs[8];
        #pragma unroll
        for (int j = 0; j < 8; j++) qs[j] = __shfl(qv, t * 8 + j, 64);

        int start = cursor[e] + blockoff[e >> 11];
        int cnt   = counts[e];
        int end   = start + cnt;

        float acc[8] = {0.f,0.f,0.f,0.f,0.f,0.f,0.f,0.f};
        float ws = 0.0f;

        for (int i = start; i < end; i += 16) {
            int iA = i + ps;
            int iB = i + 8 + ps;
            bool vA = iA < end, vB = iB < end;
            int cA = vA ? iA : start;
            int cB = vB ? iB : start;
            int sA = sorted[cA];
            int sB = sorted[cB];
            float bA = (float)bias_s[(long long)cA * 8 + t];
            float bB = (float)bias_s[(long long)cB * 8 + t];
            f16x8 kA = *(const f16x8*)(k + (long long)sA * 64 + t * 8);
            f16x8 kB = *(const f16x8*)(k + (long long)sB * 64 + t * 8);
            f16x8 vA8 = *(const f16x8*)(v + (long long)sA * 64 + t * 8);
            f16x8 vB8 = *(const f16x8*)(v + (long long)sB * 64 + t * 8);

            float dA = 0.0f, dB = 0.0f;
            #pragma unroll
            for (int j = 0; j < 8; j++) {
                dA = fmaf(qs[j], (float)kA[j], dA);
                dB = fmaf(qs[j], (float)kB[j], dB);
            }
            float wA = vA ? __expf(fmaf(dA, 0.35355339059327373f, bA)) : 0.0f;
            float wB = vB ? __expf(fmaf(dB, 0.35355339059327373f, bB)) : 0.0f;
            ws += wA + wB;
            #pragma unroll
            for (int j = 0; j < 8; j++) {
                acc[j] = fmaf(wA, (float)vA8[j], acc[j]);
                acc[j] = fmaf(wB, (float)vB8[j], acc[j]);
            }
        }

        // reduce over pair slots (lane bits 3..5), once per dst
        #pragma unroll
        for (int st = 8; st <= 32; st <<= 1) {
            #pragma unroll
            for (int j = 0; j < 8; j++) acc[j] += __shfl_xor(acc[j], st, 64);
            ws += __shfl_xor(ws, st, 64);
        }

        if (ps == 0) {
            float inv = 1.0f / (ws + 1e-16f);
            float4 o0, o1;
            o0.x = acc[0]*inv; o0.y = acc[1]*inv;
            o0.z = acc[2]*inv; o0.w = acc[3]*inv;
            o1.x = acc[4]*inv; o1.y = acc[5]*inv;
            o1.z = acc[6]*inv; o1.w = acc[7]*inv;
            *(float4*)(qmsg + (long long)e * 64 + t * 8)     = o0;
            *(float4*)(qmsg + (long long)e * 64 + t * 8 + 4) = o1;
        }
    }
}

// ---------------------------------------------------------------------------
// out = msg @ Wo + bo via MFMA, in-place on d_out.
// ---------------------------------------------------------------------------
__global__ __launch_bounds__(256) void out_mfma(
    const float* __restrict__ Wo, const float* __restrict__ bo,
    float* __restrict__ out)
{
    const int w    = threadIdx.x >> 6;
    const int lane = threadIdx.x & 63;
    const int quad = lane >> 4;
    const int m    = lane & 15;

    bf16x8 B[4][2];
    float  bov[4];
    #pragma unroll
    for (int ct = 0; ct < 4; ct++) {
        int cc = ct * 16 + m;
        bov[ct] = bo[cc];
        #pragma unroll
        for (int kb = 0; kb < 2; kb++) {
            #pragma unroll
            for (int j = 0; j < 8; j++) {
                int kk = kb * 32 + quad * 8 + j;
                B[ct][kb][j] = f2bf(Wo[kk * 64 + cc]);
            }
        }
    }

    for (int row0 = blockIdx.x * 64 + w * 16; row0 < E_N; row0 += gridDim.x * 64) {
        const float* xr = out + (long long)(row0 + m) * 64 + quad * 8;
        bf16x8 A[2];
        #pragma unroll
        for (int kb = 0; kb < 2; kb++) {
            float4 p0 = *(const float4*)(xr + kb * 32);
            float4 p1 = *(const float4*)(xr + kb * 32 + 4);
            A[kb][0] = f2bf(p0.x); A[kb][1] = f2bf(p0.y);
            A[kb][2] = f2bf(p0.z); A[kb][3] = f2bf(p0.w);
            A[kb][4] = f2bf(p1.x); A[kb][5] = f2bf(p1.y);
            A[kb][6] = f2bf(p1.z); A[kb][7] = f2bf(p1.w);
        }

        f32x4 acc[4];
        #pragma unroll
        for (int ct = 0; ct < 4; ct++) {
            acc[ct] = (f32x4){bov[ct], bov[ct], bov[ct], bov[ct]};
            acc[ct] = __builtin_amdgcn_mfma_f32_16x16x32_bf16(A[0], B[ct][0], acc[ct], 0, 0, 0);
            acc[ct] = __builtin_amdgcn_mfma_f32_16x16x32_bf16(A[1], B[ct][1], acc[ct], 0, 0, 0);
        }
        #pragma unroll
        for (int ct = 0; ct < 4; ct++) {
            #pragma unroll
            for (int i = 0; i < 4; i++) {
                out[(long long)(row0 + quad * 4 + i) * 64 + ct * 16 + m] = acc[ct][i];
            }
        }
    }
}

extern "C" void kernel_launch(void* const* d_in, const int* in_sizes, int n_in,
                              void* d_out, int out_size, void* d_ws, size_t ws_size,
                              hipStream_t stream) {
    const float* x    = (const float*)d_in[0];
    const int*   e2e  = (const int*)  d_in[1];
    const float* bias = (const float*)d_in[2];
    const float* Wq   = (const float*)d_in[3];
    const float* bq   = (const float*)d_in[4];
    const float* Wk   = (const float*)d_in[5];
    const float* bk   = (const float*)d_in[6];
    const float* Wv   = (const float*)d_in[7];
    const float* bv   = (const float*)d_in[8];
    const float* Wo   = (const float*)d_in[9];
    const float* bo   = (const float*)d_in[10];
    float* out = (float*)d_out;   // q buffer -> msg buffer -> final out (in place)

    // ws: k_h[12.8M f16] | v_h[12.8M f16] | counts | cursor | bsum | boff |
    //     sorted[3.2M int] | bias_s[25.6M f16] | bcnt[BLEN, scanned in place] |
    //     bsum2[512] | boff2[512]   (total ~120 MB)
    _Float16* kh     = (_Float16*)d_ws;
    _Float16* vh     = kh + (long long)E_N * 64;
    int*      counts = (int*)(vh + (long long)E_N * 64);
    int*      cursor = counts + E_N;
    int*      bsum   = cursor + E_N;
    int*      boff   = bsum + 512;
    int*      sorted = boff + 512;
    _Float16* bias_s = (_Float16*)(sorted + M_N);
    int*      bcnt   = (int*)(bias_s + (long long)M_N * 8);
    int*      bsum2  = bcnt + BLEN;
    int*      boff2  = bsum2 + 512;

    hipMemsetAsync(counts, 0, (size_t)E_N * sizeof(int), stream);

    qkv_mfma<<<640, 256, 0, stream>>>(x, Wq, bq, Wk, bk, Wv, bv, out, kh, vh);

    // dst-level histogram + scan (pristine; consumed by aggregate + permute)
    hist_kernel<<<M_N / 1024, 256, 0, stream>>>(e2e, counts);
    scan1_kernel<<<NB1, 256, 0, stream>>>(counts, cursor, bsum, E_N);
    scan2_kernel<<<1, 256, 0, stream>>>(bsum, boff, NB1);

    // (bucket,chunk) histogram + in-place scan -> disjoint slot ranges
    bhist_kernel<<<NCHUNK, 1024, 0, stream>>>(e2e, bcnt);
    scan1_kernel<<<NB2, 256, 0, stream>>>(bcnt, bcnt, bsum2, BLEN);
    scan2_kernel<<<1, 256, 0, stream>>>(bsum2, boff2, NB2);

    // register-payload counting sort, single-window LDS stage, streaming emit
    scatter_bucket<<<NCHUNK, 1024, 0, stream>>>(e2e, bias, bcnt, boff2,
                                                sorted, bias_s);
    bucket_permute<<<NBUCK, 512, 0, stream>>>(cursor, boff, sorted, bias_s);

    aggregate_kernel<<<8192, 256, 0, stream>>>(kh, vh, bias_s, counts, cursor,
                                               boff, sorted, out);

    out_mfma<<<640, 256, 0, stream>>>(Wo, bo, out);
}

// Round 7
// 558.707 us; speedup vs baseline: 1.3746x; 1.1672x over previous
//
#include <hip/hip_runtime.h>

#define E_N 200000
#define M_N 3200000
#define SCAN_CHUNK 2048

// bucket sort geometry (256 dst per bucket)
#define NBUCK 782       // ceil(E_N / 256)
#define NCHUNK 1000     // m-chunks (one block each)
#define CH 3200         // pairs per chunk: NCHUNK*CH == M_N
#define BLEN (NBUCK * NCHUNK)   // 782000
#define NB2 382         // ceil(BLEN / SCAN_CHUNK)
#define NP 4            // pairs per thread: ceil(CH/1024)
#define SMAX 8192       // max records per bucket in LDS (mean 4096, ~64 sigma)

typedef __attribute__((ext_vector_type(8))) short bf16x8;      // MFMA A/B frag
typedef __attribute__((ext_vector_type(4))) float f32x4;       // MFMA C/D frag
typedef __attribute__((ext_vector_type(8))) _Float16 f16x8;    // 16B of f16

// fp32 -> bf16 (round to nearest even), raw short
__device__ __forceinline__ short f2bf(float f) {
    union { float f; unsigned u; } x; x.f = f;
    unsigned r = x.u + 0x7fffu + ((x.u >> 16) & 1u);
    return (short)(r >> 16);
}

// ---------------------------------------------------------------------------
// qkv via MFMA: q (fp32, to d_out) and k/v (f16) = x @ W + b.
// One wave per 16-row stripe; block = 4 waves = 64 rows/iter. E_N % 64 == 0.
// ---------------------------------------------------------------------------
__global__ __launch_bounds__(256) void qkv_mfma(
    const float* __restrict__ x,
    const float* __restrict__ Wq, const float* __restrict__ bq,
    const float* __restrict__ Wk, const float* __restrict__ bk,
    const float* __restrict__ Wv, const float* __restrict__ bv,
    float* __restrict__ q, _Float16* __restrict__ k, _Float16* __restrict__ v)
{
    const int w    = threadIdx.x >> 6;
    const int lane = threadIdx.x & 63;
    const int quad = lane >> 4;
    const int m    = lane & 15;

    bf16x8 Bq[4][2], Bk[4][2], Bv[4][2];
    float  bqv[4], bkv[4], bvv[4];
    #pragma unroll
    for (int ct = 0; ct < 4; ct++) {
        int cc = ct * 16 + m;
        bqv[ct] = bq[cc]; bkv[ct] = bk[cc]; bvv[ct] = bv[cc];
        #pragma unroll
        for (int kb = 0; kb < 2; kb++) {
            #pragma unroll
            for (int j = 0; j < 8; j++) {
                int kk = kb * 32 + quad * 8 + j;
                Bq[ct][kb][j] = f2bf(Wq[kk * 64 + cc]);
                Bk[ct][kb][j] = f2bf(Wk[kk * 64 + cc]);
                Bv[ct][kb][j] = f2bf(Wv[kk * 64 + cc]);
            }
        }
    }

    for (int row0 = blockIdx.x * 64 + w * 16; row0 < E_N; row0 += gridDim.x * 64) {
        const float* xr = x + (long long)(row0 + m) * 64 + quad * 8;
        bf16x8 A[2];
        #pragma unroll
        for (int kb = 0; kb < 2; kb++) {
            float4 p0 = *(const float4*)(xr + kb * 32);
            float4 p1 = *(const float4*)(xr + kb * 32 + 4);
            A[kb][0] = f2bf(p0.x); A[kb][1] = f2bf(p0.y);
            A[kb][2] = f2bf(p0.z); A[kb][3] = f2bf(p0.w);
            A[kb][4] = f2bf(p1.x); A[kb][5] = f2bf(p1.y);
            A[kb][6] = f2bf(p1.z); A[kb][7] = f2bf(p1.w);
        }

        #pragma unroll
        for (int ct = 0; ct < 4; ct++) {
            f32x4 aq = {bqv[ct], bqv[ct], bqv[ct], bqv[ct]};
            f32x4 ak = {bkv[ct], bkv[ct], bkv[ct], bkv[ct]};
            f32x4 av = {bvv[ct], bvv[ct], bvv[ct], bvv[ct]};
            aq = __builtin_amdgcn_mfma_f32_16x16x32_bf16(A[0], Bq[ct][0], aq, 0, 0, 0);
            aq = __builtin_amdgcn_mfma_f32_16x16x32_bf16(A[1], Bq[ct][1], aq, 0, 0, 0);
            ak = __builtin_amdgcn_mfma_f32_16x16x32_bf16(A[0], Bk[ct][0], ak, 0, 0, 0);
            ak = __builtin_amdgcn_mfma_f32_16x16x32_bf16(A[1], Bk[ct][1], ak, 0, 0, 0);
            av = __builtin_amdgcn_mfma_f32_16x16x32_bf16(A[0], Bv[ct][0], av, 0, 0, 0);
            av = __builtin_amdgcn_mfma_f32_16x16x32_bf16(A[1], Bv[ct][1], av, 0, 0, 0);
            #pragma unroll
            for (int i = 0; i < 4; i++) {
                long long off = (long long)(row0 + quad * 4 + i) * 64 + ct * 16 + m;
                q[off] = aq[i];
                k[off] = (_Float16)ak[i];
                v[off] = (_Float16)av[i];
            }
        }
    }
}

// ---------------------------------------------------------------------------
// generic 2-level exclusive scan (chunk size SCAN_CHUNK). In-place safe.
// ---------------------------------------------------------------------------
__global__ __launch_bounds__(256) void scan1_kernel(
    const int* __restrict__ counts, int* __restrict__ cursor,
    int* __restrict__ blocksums, int len)
{
    __shared__ int s[256];
    const int t = threadIdx.x;
    const int base = blockIdx.x * SCAN_CHUNK + t * 8;

    int vals[8];
    int tot = 0;
    #pragma unroll
    for (int j = 0; j < 8; j++) {
        int idx = base + j;
        vals[j] = (idx < len) ? counts[idx] : 0;
        tot += vals[j];
    }
    s[t] = tot;
    __syncthreads();
    for (int off = 1; off < 256; off <<= 1) {
        int add = (t >= off) ? s[t - off] : 0;
        __syncthreads();
        s[t] += add;
        __syncthreads();
    }
    int excl = (t == 0) ? 0 : s[t - 1];
    if (t == 255) blocksums[blockIdx.x] = s[255];

    int run = excl;
    #pragma unroll
    for (int j = 0; j < 8; j++) {
        int idx = base + j;
        if (idx < len) cursor[idx] = run;
        run += vals[j];
    }
}

// exclusive scan of up to 1024 block sums (4/thread at 256 threads)
__global__ __launch_bounds__(256) void scan2_kernel(
    const int* __restrict__ blocksums, int* __restrict__ blockoff, int nb)
{
    __shared__ int s[256];
    const int t = threadIdx.x;
    int vals[4];
    int tot = 0;
    #pragma unroll
    for (int u = 0; u < 4; u++) {
        int idx = t * 4 + u;
        vals[u] = (idx < nb) ? blocksums[idx] : 0;
        tot += vals[u];
    }
    s[t] = tot;
    __syncthreads();
    for (int off = 1; off < 256; off <<= 1) {
        int add = (t >= off) ? s[t - off] : 0;
        __syncthreads();
        s[t] += add;
        __syncthreads();
    }
    int run = (t == 0) ? 0 : s[t - 1];
    #pragma unroll
    for (int u = 0; u < 4; u++) {
        int idx = t * 4 + u;
        if (idx < nb) blockoff[idx] = run;
        run += vals[u];
    }
}

// ---------------------------------------------------------------------------
// per-(bucket,chunk) histogram: bucket = dst>>8, one block per m-chunk.
// ---------------------------------------------------------------------------
__global__ __launch_bounds__(1024) void bhist_kernel(
    const int* __restrict__ e2e, int* __restrict__ bcnt)
{
    __shared__ int lc[NBUCK];
    const int c = blockIdx.x;
    for (int i = threadIdx.x; i < NBUCK; i += 1024) lc[i] = 0;
    __syncthreads();
    const int m0 = c * CH;
    for (int i = threadIdx.x * 4; i < CH; i += 4096) {
        int4 d = *(const int4*)(e2e + M_N + m0 + i);
        atomicAdd(&lc[d.x >> 8], 1);
        atomicAdd(&lc[d.y >> 8], 1);
        atomicAdd(&lc[d.z >> 8], 1);
        atomicAdd(&lc[d.w >> 8], 1);
    }
    __syncthreads();
    for (int i = threadIdx.x; i < NBUCK; i += 1024) bcnt[i * NCHUNK + c] = lc[i];
}

// ---------------------------------------------------------------------------
// scatter: NP=4 payload in registers, whole chunk staged in ONE LDS window.
// Coalesced load -> LDS hist -> scan -> rank -> stage bias + bk -> coalesced
// emit -> re-stage meta (same pool) -> coalesced emit.
// meta = (dst_low8 << 18) | src  (src < 2^18).
// pk = (bucket << 12) | j  (bucket < 782, j < 3200), -1 = invalid.
// ---------------------------------------------------------------------------
__global__ __launch_bounds__(1024, 4) void scatter_bucket(
    const int* __restrict__ e2e, const float* __restrict__ bias,
    const int* __restrict__ bcur0, const int* __restrict__ boff2,
    int* __restrict__ meta, _Float16* __restrict__ bias_s)
{
    __shared__ int gbase[NBUCK];                       // slot base minus lbase
    __shared__ unsigned short bk[CH];                  // bucket per rank j
    __shared__ char pool[CH * 16] __attribute__((aligned(16)));   // 50 KB union
    int*   cnt     = (int*)pool;                       // [NBUCK] phases 1-3
    int*   s       = (int*)(pool + 4096);              // [1024]  phase 2
    f16x8* stage_b = (f16x8*)pool;                     // [CH]    phase 4a
    int*   stage_m = (int*)pool;                       // [CH]    phase 4b

    const int c = blockIdx.x;
    const int t = threadIdx.x;
    const int m0 = c * CH;

    for (int b = t; b < NBUCK; b += 1024) {
        cnt[b] = 0;
        int idx = b * NCHUNK + c;
        gbase[b] = bcur0[idx] + boff2[idx >> 11];
    }
    __syncthreads();

    // phase 1: coalesced loads; payload -> registers; bucket histogram
    int   mt[NP];
    int   pk[NP];
    f16x8 bb[NP];
    #pragma unroll
    for (int r = 0; r < NP; r++) {
        int i = t + r * 1024;
        pk[r] = -1;
        if (i < CH) {
            int m = m0 + i;
            int dst = e2e[M_N + m];
            int src = e2e[m];
            int b = dst >> 8;
            pk[r] = b << 12;                  // rank filled in phase 3
            mt[r] = ((dst & 255) << 18) | src;
            float4 b0 = *(const float4*)(bias + (long long)m * 8);
            float4 b1 = *(const float4*)(bias + (long long)m * 8 + 4);
            f16x8 xx;
            xx[0] = (_Float16)b0.x; xx[1] = (_Float16)b0.y;
            xx[2] = (_Float16)b0.z; xx[3] = (_Float16)b0.w;
            xx[4] = (_Float16)b1.x; xx[5] = (_Float16)b1.y;
            xx[6] = (_Float16)b1.z; xx[7] = (_Float16)b1.w;
            bb[r] = xx;
            atomicAdd(&cnt[b], 1);
        }
    }
    __syncthreads();

    // phase 2: exclusive scan over NBUCK buckets; fold lbase into gbase
    int v = (t < NBUCK) ? cnt[t] : 0;
    s[t] = v;
    __syncthreads();
    for (int off = 1; off < 1024; off <<= 1) {
        int add = (t >= off) ? s[t - off] : 0;
        __syncthreads();
        s[t] += add;
        __syncthreads();
    }
    if (t < NBUCK) {
        int excl = (t == 0) ? 0 : s[t - 1];
        gbase[t] -= excl;          // slot = gbase[b] + j
        cnt[t] = excl;             // running cursor (global chunk rank j)
    }
    __syncthreads();

    // phase 3: claim rank j per held pair
    #pragma unroll
    for (int r = 0; r < NP; r++) {
        if (pk[r] >= 0) {
            int b = pk[r] >> 12;
            int j = atomicAdd(&cnt[b], 1);
            pk[r] = (b << 12) | j;
        }
    }
    __syncthreads();   // cnt dead; pool reused as stage

    // phase 4a: stage bias + bk by rank, emit coalesced in rank order
    #pragma unroll
    for (int r = 0; r < NP; r++) {
        if (pk[r] >= 0) {
            int j = pk[r] & 4095;
            stage_b[j] = bb[r];
            bk[j] = (unsigned short)(pk[r] >> 12);
        }
    }
    __syncthreads();
    for (int j = t; j < CH; j += 1024) {
        int slot = gbase[bk[j]] + j;
        *(f16x8*)(bias_s + (long long)slot * 8) = stage_b[j];
    }
    __syncthreads();

    // phase 4b: re-stage meta in same pool (bk persists), emit coalesced
    #pragma unroll
    for (int r = 0; r < NP; r++) {
        if (pk[r] >= 0) stage_m[pk[r] & 4095] = mt[r];
    }
    __syncthreads();
    for (int j = t; j < CH; j += 1024) {
        meta[gbase[bk[j]] + j] = stage_m[j];
    }
}

// ---------------------------------------------------------------------------
// aggregate_bucket: one block per 256-dst bucket (512 thr, 8 waves).
// Phase A: load bucket's meta to LDS, per-dst hist -> scan -> rank table ord[]
//          (the old bucket_permute, minus its 128 MB global round-trip).
// Phase B: each wave aggregates 32 dsts with the 8-slot structure: lane
//          (ps,th) owns pair slot ps, head th; private 8-wide partials;
//          one 3-stage shfl_xor butterfly per dst.
// Bucket bounds come from the scanned bcnt (no dst-level scan needed).
// ---------------------------------------------------------------------------
__global__ __launch_bounds__(512, 2) void aggregate_bucket(
    const _Float16* __restrict__ k, const _Float16* __restrict__ v,
    const _Float16* __restrict__ bias_s,
    const int* __restrict__ bstart, const int* __restrict__ boff2,
    const int* __restrict__ meta,
    float* __restrict__ qmsg)
{
    __shared__ int smeta[SMAX];           // 32 KB
    __shared__ unsigned short ord[SMAX];  // 16 KB
    __shared__ int cnt[256];              // hist -> cursor -> segment END
    __shared__ int scn[256];
    __shared__ int base[256];             // segment start
    const int b = blockIdx.x;
    const int t = threadIdx.x;

    const int i0 = b * NCHUNK;
    const int bs = bstart[i0] + boff2[i0 >> 11];
    int be;
    if (b + 1 < NBUCK) {
        int i1 = (b + 1) * NCHUNK;
        be = bstart[i1] + boff2[i1 >> 11];
    } else {
        be = M_N;
    }
    int n = be - bs;
    if (n > SMAX) n = SMAX;   // ~64 sigma; memory-safety clamp only

    if (t < 256) cnt[t] = 0;
    __syncthreads();
    #pragma unroll
    for (int r = 0; r < SMAX / 512; r++) {
        int i = t + r * 512;
        if (i < n) {
            int mm = meta[bs + i];
            smeta[i] = mm;
            atomicAdd(&cnt[mm >> 18], 1);
        }
    }
    __syncthreads();
    if (t < 256) scn[t] = cnt[t];
    __syncthreads();
    for (int off = 1; off < 256; off <<= 1) {
        int vv = 0;
        if (t < 256 && t >= off) vv = scn[t - off];
        __syncthreads();
        if (t < 256) scn[t] += vv;
        __syncthreads();
    }
    if (t < 256) {
        int excl = scn[t] - cnt[t];
        base[t] = excl;
        cnt[t]  = excl;           // running cursor
    }
    __syncthreads();
    #pragma unroll
    for (int r = 0; r < SMAX / 512; r++) {
        int i = t + r * 512;
        if (i < n) {
            int p = atomicAdd(&cnt[smeta[i] >> 18], 1);
            ord[p] = (unsigned short)i;
        }
    }
    __syncthreads();              // cnt[el] now == segment end

    // ---- phase B ----
    const int wid  = t >> 6;
    const int lane = t & 63;
    const int ps   = lane >> 3;   // pair slot 0..7
    const int th   = lane & 7;    // head 0..7
    const int d0   = b << 8;

    for (int u = 0; u < 32; u++) {
        int el = (wid << 5) + u;
        int e  = d0 + el;
        if (e >= E_N) break;      // only trailing waves of the last bucket

        int st = base[el];
        int en = cnt[el];

        float qv = qmsg[(long long)e * 64 + lane];
        float qs[8];
        #pragma unroll
        for (int j = 0; j < 8; j++) qs[j] = __shfl(qv, th * 8 + j, 64);

        float acc[8] = {0.f,0.f,0.f,0.f,0.f,0.f,0.f,0.f};
        float ws = 0.0f;

        for (int i = st; i < en; i += 16) {
            int iA = i + ps;
            int iB = i + 8 + ps;
            bool vA = iA < en, vB = iB < en;
            int cA = vA ? iA : st;
            int cB = vB ? iB : st;
            int rA = ord[cA];
            int rB = ord[cB];
            int sA = smeta[rA] & 0x3FFFF;
            int sB = smeta[rB] & 0x3FFFF;
            float bA = (float)bias_s[(long long)(bs + rA) * 8 + th];
            float bB = (float)bias_s[(long long)(bs + rB) * 8 + th];
            f16x8 kA = *(const f16x8*)(k + (long long)sA * 64 + th * 8);
            f16x8 kB = *(const f16x8*)(k + (long long)sB * 64 + th * 8);
            f16x8 vA8 = *(const f16x8*)(v + (long long)sA * 64 + th * 8);
            f16x8 vB8 = *(const f16x8*)(v + (long long)sB * 64 + th * 8);

            float dA = 0.0f, dB = 0.0f;
            #pragma unroll
            for (int j = 0; j < 8; j++) {
                dA = fmaf(qs[j], (float)kA[j], dA);
                dB = fmaf(qs[j], (float)kB[j], dB);
            }
            float wA = vA ? __expf(fmaf(dA, 0.35355339059327373f, bA)) : 0.0f;
            float wB = vB ? __expf(fmaf(dB, 0.35355339059327373f, bB)) : 0.0f;
            ws += wA + wB;
            #pragma unroll
            for (int j = 0; j < 8; j++) {
                acc[j] = fmaf(wA, (float)vA8[j], acc[j]);
                acc[j] = fmaf(wB, (float)vB8[j], acc[j]);
            }
        }

        // reduce over pair slots (lane bits 3..5), once per dst
        #pragma unroll
        for (int stg = 8; stg <= 32; stg <<= 1) {
            #pragma unroll
            for (int j = 0; j < 8; j++) acc[j] += __shfl_xor(acc[j], stg, 64);
            ws += __shfl_xor(ws, stg, 64);
        }

        if (ps == 0) {
            float inv = 1.0f / (ws + 1e-16f);
            float4 o0, o1;
            o0.x = acc[0]*inv; o0.y = acc[1]*inv;
            o0.z = acc[2]*inv; o0.w = acc[3]*inv;
            o1.x = acc[4]*inv; o1.y = acc[5]*inv;
            o1.z = acc[6]*inv; o1.w = acc[7]*inv;
            *(float4*)(qmsg + (long long)e * 64 + th * 8)     = o0;
            *(float4*)(qmsg + (long long)e * 64 + th * 8 + 4) = o1;
        }
    }
}

// ---------------------------------------------------------------------------
// out = msg @ Wo + bo via MFMA, in-place on d_out.
// ---------------------------------------------------------------------------
__global__ __launch_bounds__(256) void out_mfma(
    const float* __restrict__ Wo, const float* __restrict__ bo,
    float* __restrict__ out)
{
    const int w    = threadIdx.x >> 6;
    const int lane = threadIdx.x & 63;
    const int quad = lane >> 4;
    const int m    = lane & 15;

    bf16x8 B[4][2];
    float  bov[4];
    #pragma unroll
    for (int ct = 0; ct < 4; ct++) {
        int cc = ct * 16 + m;
        bov[ct] = bo[cc];
        #pragma unroll
        for (int kb = 0; kb < 2; kb++) {
            #pragma unroll
            for (int j = 0; j < 8; j++) {
                int kk = kb * 32 + quad * 8 + j;
                B[ct][kb][j] = f2bf(Wo[kk * 64 + cc]);
            }
        }
    }

    for (int row0 = blockIdx.x * 64 + w * 16; row0 < E_N; row0 += gridDim.x * 64) {
        const float* xr = out + (long long)(row0 + m) * 64 + quad * 8;
        bf16x8 A[2];
        #pragma unroll
        for (int kb = 0; kb < 2; kb++) {
            float4 p0 = *(const float4*)(xr + kb * 32);
            float4 p1 = *(const float4*)(xr + kb * 32 + 4);
            A[kb][0] = f2bf(p0.x); A[kb][1] = f2bf(p0.y);
            A[kb][2] = f2bf(p0.z); A[kb][3] = f2bf(p0.w);
            A[kb][4] = f2bf(p1.x); A[kb][5] = f2bf(p1.y);
            A[kb][6] = f2bf(p1.z); A[kb][7] = f2bf(p1.w);
        }

        f32x4 acc[4];
        #pragma unroll
        for (int ct = 0; ct < 4; ct++) {
            acc[ct] = (f32x4){bov[ct], bov[ct], bov[ct], bov[ct]};
            acc[ct] = __builtin_amdgcn_mfma_f32_16x16x32_bf16(A[0], B[ct][0], acc[ct], 0, 0, 0);
            acc[ct] = __builtin_amdgcn_mfma_f32_16x16x32_bf16(A[1], B[ct][1], acc[ct], 0, 0, 0);
        }
        #pragma unroll
        for (int ct = 0; ct < 4; ct++) {
            #pragma unroll
            for (int i = 0; i < 4; i++) {
                out[(long long)(row0 + quad * 4 + i) * 64 + ct * 16 + m] = acc[ct][i];
            }
        }
    }
}

extern "C" void kernel_launch(void* const* d_in, const int* in_sizes, int n_in,
                              void* d_out, int out_size, void* d_ws, size_t ws_size,
                              hipStream_t stream) {
    const float* x    = (const float*)d_in[0];
    const int*   e2e  = (const int*)  d_in[1];
    const float* bias = (const float*)d_in[2];
    const float* Wq   = (const float*)d_in[3];
    const float* bq   = (const float*)d_in[4];
    const float* Wk   = (const float*)d_in[5];
    const float* bk   = (const float*)d_in[6];
    const float* Wv   = (const float*)d_in[7];
    const float* bv   = (const float*)d_in[8];
    const float* Wo   = (const float*)d_in[9];
    const float* bo   = (const float*)d_in[10];
    float* out = (float*)d_out;   // q buffer -> msg buffer -> final out (in place)

    // ws: k_h[12.8M f16] | v_h[12.8M f16] | meta[3.2M int] | bias_s[25.6M f16]
    //     | bcnt[BLEN, scanned in place] | bsum2[512] | boff2[512]  (~119 MB)
    _Float16* kh     = (_Float16*)d_ws;
    _Float16* vh     = kh + (long long)E_N * 64;
    int*      meta   = (int*)(vh + (long long)E_N * 64);
    _Float16* bias_s = (_Float16*)(meta + M_N);
    int*      bcnt   = (int*)(bias_s + (long long)M_N * 8);
    int*      bsum2  = bcnt + BLEN;
    int*      boff2  = bsum2 + 512;

    qkv_mfma<<<640, 256, 0, stream>>>(x, Wq, bq, Wk, bk, Wv, bv, out, kh, vh);

    // (bucket,chunk) histogram + in-place scan -> disjoint slot ranges
    bhist_kernel<<<NCHUNK, 1024, 0, stream>>>(e2e, bcnt);
    scan1_kernel<<<NB2, 256, 0, stream>>>(bcnt, bcnt, bsum2, BLEN);
    scan2_kernel<<<1, 256, 0, stream>>>(bsum2, boff2, NB2);

    // register-payload counting sort -> bucket-grouped meta/bias_s streams
    scatter_bucket<<<NCHUNK, 1024, 0, stream>>>(e2e, bias, bcnt, boff2,
                                                meta, bias_s);

    // per-bucket in-LDS dst-sort + softmax aggregation (no global permute)
    aggregate_bucket<<<NBUCK, 512, 0, stream>>>(kh, vh, bias_s, bcnt, boff2,
                                                meta, out);

    out_mfma<<<640, 256, 0, stream>>>(Wo, bo, out);
}